// Round 1
// 595.445 us; speedup vs baseline: 1.1487x; 1.1487x over previous
//
#include <hip/hip_runtime.h>
#include <math.h>

#define S_LEN 2048
#define HID 2048
#define NH 16
#define NKV 4
#define DH 128
#define CACHE_LEN 2048
#define QKV_W 3072   // q(2048) | k(512) | v(512) packed per row
#define SCALE 0.08838834764831845f
#define EPS 1e-6f
#define LYRA_C 12.0f // fixed softmax max-bound: |scores| <= ~19, exp(s-12) safe

typedef short bf16x8 __attribute__((ext_vector_type(8)));
typedef float f32x4 __attribute__((ext_vector_type(4)));

static __device__ __forceinline__ short f2bf(float x) {
  union { float f; unsigned u; } v; v.f = x;
  unsigned r = (v.u + 0x7FFF + ((v.u >> 16) & 1)) >> 16;
  return (short)r;
}

#define GLDS16(g, l)                                                      \
  __builtin_amdgcn_global_load_lds(                                       \
      (const __attribute__((address_space(1))) unsigned int*)(g),         \
      (__attribute__((address_space(3))) unsigned int*)(l), 16, 0, 0)

// ---------------------------------------------------------------------------
// fp32 -> bf16 pack, 8 elements/thread.
// ---------------------------------------------------------------------------
__global__ __launch_bounds__(256) void pack_bf16(
    const float* __restrict__ src, short* __restrict__ dst) {
  const int i = (blockIdx.x * 256 + threadIdx.x) * 8;
  float4 a = *(const float4*)(src + i);
  float4 b = *(const float4*)(src + i + 4);
  bf16x8 o;
  o[0] = f2bf(a.x); o[1] = f2bf(a.y); o[2] = f2bf(a.z); o[3] = f2bf(a.w);
  o[4] = f2bf(b.x); o[5] = f2bf(b.y); o[6] = f2bf(b.z); o[7] = f2bf(b.w);
  *(bf16x8*)(dst + i) = o;
}

// ---------------------------------------------------------------------------
// bf16 MFMA GEMM: C[M x N] fp32 = A[M x K]bf16 * B[N x K]bf16^T.
// ---------------------------------------------------------------------------
__global__ __launch_bounds__(256) void gemm_bf16(
    const short* __restrict__ A, const short* __restrict__ B,
    float* __restrict__ C, int K, int ldc) {
  __shared__ short sA[4096];
  __shared__ short sB[4096];
  const int t = threadIdx.x;
  const int w = t >> 6;
  const int lane = t & 63;
  const int quad = lane >> 4;
  const int l16 = lane & 15;
  const int tm = blockIdx.y * 128;
  const int tn = blockIdx.x * 128;
  const int srow = lane >> 2;
  const int scol = (lane & 3) * 8;
  const int mblk = (w & 1) * 64;
  const int nblk = (w >> 1) * 64;
  f32x4 acc[4][4];
#pragma unroll
  for (int i = 0; i < 4; ++i)
#pragma unroll
    for (int j = 0; j < 4; ++j) acc[i][j] = (f32x4){0.f, 0.f, 0.f, 0.f};

  const short* Ab = A + (size_t)(tm + w * 32 + srow) * K + scol;
  const short* Bb = B + (size_t)(tn + w * 32 + srow) * K + scol;
  const size_t rstep = (size_t)16 * K;

  for (int k0 = 0; k0 < K; k0 += 32) {
    GLDS16(Ab + k0, sA + (w * 2 + 0) * 512);
    GLDS16(Ab + rstep + k0, sA + (w * 2 + 1) * 512);
    GLDS16(Bb + k0, sB + (w * 2 + 0) * 512);
    GLDS16(Bb + rstep + k0, sB + (w * 2 + 1) * 512);
    __syncthreads();
    bf16x8 af[4], bfv[4];
#pragma unroll
    for (int ms = 0; ms < 4; ++ms)
      af[ms] = *(const bf16x8*)&sA[(mblk + ms * 16 + l16) * 32 + quad * 8];
#pragma unroll
    for (int ns = 0; ns < 4; ++ns)
      bfv[ns] = *(const bf16x8*)&sB[(nblk + ns * 16 + l16) * 32 + quad * 8];
#pragma unroll
    for (int ms = 0; ms < 4; ++ms)
#pragma unroll
      for (int ns = 0; ns < 4; ++ns)
        acc[ms][ns] = __builtin_amdgcn_mfma_f32_16x16x32_bf16(
            af[ms], bfv[ns], acc[ms][ns], 0, 0, 0);
    __syncthreads();
  }
#pragma unroll
  for (int ms = 0; ms < 4; ++ms)
#pragma unroll
    for (int ns = 0; ns < 4; ++ns) {
      const int row = tm + mblk + ms * 16 + quad * 4;
      const int col = tn + nblk + ns * 16 + l16;
#pragma unroll
      for (int r = 0; r < 4; ++r)
        C[(size_t)(row + r) * ldc + col] = acc[ms][ns][r];
    }
}

// ---------------------------------------------------------------------------
// RMSNorm(+1+w) then RoPE, in-place on q (16 heads) and k (4 heads).
// ---------------------------------------------------------------------------
__global__ __launch_bounds__(256) void rms_rope(
    float* __restrict__ qkv,
    const float* __restrict__ cosb, const float* __restrict__ sinb,
    const float* __restrict__ qw, const float* __restrict__ kw) {
  const int unit = blockIdx.x * 4 + (threadIdx.x >> 6);
  const int lane = threadIdx.x & 63;
  const int total_q = S_LEN * NH;
  float* base;
  const float* w;
  int pos;
  if (unit < total_q) {
    pos = unit >> 4;
    int head = unit & 15;
    base = qkv + (size_t)pos * QKV_W + head * DH;
    w = qw;
  } else {
    int u = unit - total_q;
    pos = u >> 2;
    int head = u & 3;
    base = qkv + (size_t)pos * QKV_W + 2048 + head * DH;
    w = kw;
  }
  float x0 = base[lane];
  float x1 = base[lane + 64];
  float ss = x0 * x0 + x1 * x1;
#pragma unroll
  for (int off = 32; off > 0; off >>= 1) ss += __shfl_xor(ss, off);
  float r = rsqrtf(ss * (1.0f / 128.0f) + EPS);
  float n0 = x0 * r * (1.0f + w[lane]);
  float n1 = x1 * r * (1.0f + w[lane + 64]);
  float c0 = cosb[(size_t)pos * DH + lane];
  float c1 = cosb[(size_t)pos * DH + lane + 64];
  float s0 = sinb[(size_t)pos * DH + lane];
  float s1 = sinb[(size_t)pos * DH + lane + 64];
  base[lane]      = n0 * c0 - n1 * s0;
  base[lane + 64] = n1 * c1 + n0 * s1;
}

// ---------------------------------------------------------------------------
// Pack K (cache ++ roped k) -> bf16 Kbf[4][4096][128], PRE-SWIZZLED within
// each 128-elem row: element d stored at d ^ ((key&7)<<3).  global_load_lds
// then copies rows linearly and the swizzled ds_read_b128 is conflict-free.
// ---------------------------------------------------------------------------
__global__ __launch_bounds__(256) void pack_k(
    const float* __restrict__ qkv, const float* __restrict__ kcache,
    short* __restrict__ Kbf) {
  const int idx = blockIdx.x * 256 + threadIdx.x;
  const int e4 = idx * 4;
  const int kvh = e4 >> 19;
  const int rem = e4 & ((1 << 19) - 1);
  const int key = rem >> 7;
  const int d = rem & 127;
  float4 v;
  if (key < CACHE_LEN)
    v = *(const float4*)(kcache + (((size_t)kvh * CACHE_LEN + key) << 7) + d);
  else
    v = *(const float4*)(qkv + (size_t)(key - CACHE_LEN) * QKV_W + 2048 + kvh * DH + d);
  short4 o;
  o.x = f2bf(v.x); o.y = f2bf(v.y); o.z = f2bf(v.z); o.w = f2bf(v.w);
  const int dsw = d ^ ((key & 7) << 3);       // in-row XOR swizzle (8-elem units)
  *(short4*)(Kbf + (size_t)(e4 - d) + dsw) = o;
}

// ---------------------------------------------------------------------------
// Pack V transposed -> bf16 Vt[4][128][4096], PRE-SWIZZLED within each
// 64-key chunk: key c stored at c ^ ((d&7)<<3).
// ---------------------------------------------------------------------------
__global__ __launch_bounds__(256) void pack_vt(
    const float* __restrict__ qkv, const float* __restrict__ vcache,
    short* __restrict__ Vt) {
  __shared__ float tile[64][65];
  const int key0 = blockIdx.x * 64;
  const int d0 = blockIdx.y * 64;
  const int kvh = blockIdx.z;
  const int t = threadIdx.x;
  const int c = t & 63;
  const int r0 = t >> 6;
#pragma unroll
  for (int i = 0; i < 16; ++i) {
    int r = r0 + i * 4;
    int key = key0 + r;
    float v;
    if (key < CACHE_LEN)
      v = vcache[(((size_t)kvh * CACHE_LEN + key) << 7) + d0 + c];
    else
      v = qkv[(size_t)(key - CACHE_LEN) * QKV_W + 2560 + kvh * DH + d0 + c];
    tile[r][c] = v;
  }
  __syncthreads();
#pragma unroll
  for (int i = 0; i < 16; ++i) {
    int wr = r0 + i * 4;
    int csw = c ^ (((d0 + wr) & 7) << 3);     // in-chunk XOR swizzle
    Vt[((size_t)kvh * DH + d0 + wr) * 4096 + key0 + csw] = f2bf(tile[c][wr]);
  }
}

// ---------------------------------------------------------------------------
// Vanilla scores (causal) — fp32 (output 1 accuracy)
// ---------------------------------------------------------------------------
__global__ __launch_bounds__(256) void vscore_gemm(
    const float* __restrict__ qkv, float* __restrict__ wout) {
  const int bx = blockIdx.x, by = blockIdx.y, h = blockIdx.z;
  if (bx > by) return;
  __shared__ float As[8][132];
  __shared__ float Bs[8][132];
  const int t = threadIdx.x;
  const int lr = t >> 1;
  const int lc = (t & 1) * 4;
  const float* Ap = qkv + h * DH + (size_t)(by * 128 + lr) * QKV_W + lc;
  const float* Bp = qkv + 2048 + (h >> 1) * DH + (size_t)(bx * 128 + lr) * QKV_W + lc;
  const int tx = t & 15;
  const int ty = t >> 4;
  float acc[8][8];
#pragma unroll
  for (int i = 0; i < 8; ++i)
#pragma unroll
    for (int j = 0; j < 8; ++j) acc[i][j] = 0.f;
  for (int k0 = 0; k0 < DH; k0 += 8) {
    float4 av = *(const float4*)(Ap + k0);
    float4 bv = *(const float4*)(Bp + k0);
    __syncthreads();
    As[lc + 0][lr] = av.x; As[lc + 1][lr] = av.y;
    As[lc + 2][lr] = av.z; As[lc + 3][lr] = av.w;
    Bs[lc + 0][lr] = bv.x; Bs[lc + 1][lr] = bv.y;
    Bs[lc + 2][lr] = bv.z; Bs[lc + 3][lr] = bv.w;
    __syncthreads();
#pragma unroll
    for (int k = 0; k < 8; ++k) {
      float4 a0 = *(const float4*)&As[k][ty * 4];
      float4 a1 = *(const float4*)&As[k][64 + ty * 4];
      float4 b0 = *(const float4*)&Bs[k][tx * 4];
      float4 b1 = *(const float4*)&Bs[k][64 + tx * 4];
      float ar[8] = {a0.x, a0.y, a0.z, a0.w, a1.x, a1.y, a1.z, a1.w};
      float br[8] = {b0.x, b0.y, b0.z, b0.w, b1.x, b1.y, b1.z, b1.w};
#pragma unroll
      for (int i = 0; i < 8; ++i)
#pragma unroll
        for (int j = 0; j < 8; ++j)
          acc[i][j] = fmaf(ar[i], br[j], acc[i][j]);
    }
  }
  float* Ch = wout + (size_t)h * S_LEN * S_LEN;
#pragma unroll
  for (int ih = 0; ih < 2; ++ih)
#pragma unroll
    for (int i = 0; i < 4; ++i) {
      int row = by * 128 + ih * 64 + ty * 4 + i;
      int ai = ih * 4 + i;
      float* Crow = Ch + (size_t)row * S_LEN + bx * 128;
      *(float4*)(Crow + tx * 4) =
          make_float4(acc[ai][0] * SCALE, acc[ai][1] * SCALE,
                      acc[ai][2] * SCALE, acc[ai][3] * SCALE);
      *(float4*)(Crow + 64 + tx * 4) =
          make_float4(acc[ai][4] * SCALE, acc[ai][5] * SCALE,
                      acc[ai][6] * SCALE, acc[ai][7] * SCALE);
    }
}

// ---------------------------------------------------------------------------
// Row softmax over s[0..row]; zeros for j>row.
// ---------------------------------------------------------------------------
__global__ __launch_bounds__(256) void vsoftmax(float* __restrict__ wout) {
  const int row = blockIdx.x;
  const int h = blockIdx.y;
  float* p = wout + (size_t)h * S_LEN * S_LEN + (size_t)row * S_LEN;
  const int n = row + 1;
  const int t = threadIdx.x;
  const int lane = t & 63, wid = t >> 6;
  __shared__ float red[4];
  float x[8];
#pragma unroll
  for (int i = 0; i < 8; ++i) {
    int j = t + i * 256;
    x[i] = (j < n) ? p[j] : -INFINITY;
  }
  float m = -INFINITY;
#pragma unroll
  for (int i = 0; i < 8; ++i) m = fmaxf(m, x[i]);
#pragma unroll
  for (int off = 32; off > 0; off >>= 1) m = fmaxf(m, __shfl_xor(m, off));
  if (lane == 0) red[wid] = m;
  __syncthreads();
  m = fmaxf(fmaxf(red[0], red[1]), fmaxf(red[2], red[3]));
  __syncthreads();
  float l = 0.f;
#pragma unroll
  for (int i = 0; i < 8; ++i) {
    x[i] = expf(x[i] - m);
    l += x[i];
  }
#pragma unroll
  for (int off = 32; off > 0; off >>= 1) l += __shfl_xor(l, off);
  if (lane == 0) red[wid] = l;
  __syncthreads();
  l = (red[0] + red[1]) + (red[2] + red[3]);
  const float inv = 1.0f / l;
#pragma unroll
  for (int i = 0; i < 8; ++i) {
    int j = t + i * 256;
    if (j < n) p[j] = x[i] * inv;
  }
  for (int j = n + t; j < S_LEN; j += 256) p[j] = 0.f;
}

// ---------------------------------------------------------------------------
// Vanilla output via bf16 MFMA: O[h][rows 16] = P[16 x kend] * V[kend x 128].
// V reads apply the pack_vt in-chunk XOR swizzle.
// ---------------------------------------------------------------------------
__global__ __launch_bounds__(64) void vout_mfma(
    const float* __restrict__ wout, const short* __restrict__ Vtb,
    short* __restrict__ combined_bf) {
  const int qt = blockIdx.x;   // 0..127
  const int h = blockIdx.y;    // 0..7
  const int kvh = h >> 1;
  const int lane = threadIdx.x;
  const int quad = lane >> 4;
  const int l16 = lane & 15;
  const int row0 = qt * 16;
  const int swx = (l16 & 7) << 3;   // element-index XOR (d&7 == l16&7)
  const float* Wr =
      wout + (size_t)h * S_LEN * S_LEN + (size_t)(row0 + l16) * S_LEN + quad * 8;
  const short* Vb = Vtb + (size_t)kvh * DH * 4096 + 2048;  // current-v keys
  f32x4 acc[8];
#pragma unroll
  for (int i = 0; i < 8; ++i) acc[i] = (f32x4){0.f, 0.f, 0.f, 0.f};
  const int kend = row0 + 16;
  for (int k0 = 0; k0 < kend; k0 += 32) {
    float4 a0 = *(const float4*)(Wr + k0);
    float4 a1 = *(const float4*)(Wr + k0 + 4);
    bf16x8 af;
    af[0] = f2bf(a0.x); af[1] = f2bf(a0.y); af[2] = f2bf(a0.z); af[3] = f2bf(a0.w);
    af[4] = f2bf(a1.x); af[5] = f2bf(a1.y); af[6] = f2bf(a1.z); af[7] = f2bf(a1.w);
#pragma unroll
    for (int t8 = 0; t8 < 8; ++t8) {
      bf16x8 bv = *(const bf16x8*)(
          Vb + (size_t)(t8 * 16 + l16) * 4096 + ((k0 + quad * 8) ^ swx));
      acc[t8] = __builtin_amdgcn_mfma_f32_16x16x32_bf16(af, bv, acc[t8], 0, 0, 0);
    }
  }
  const int rbase = row0 + quad * 4;
#pragma unroll
  for (int t8 = 0; t8 < 8; ++t8)
#pragma unroll
    for (int r = 0; r < 4; ++r)
      combined_bf[(size_t)(rbase + r) * HID + h * DH + t8 * 16 + l16] =
          f2bf(acc[t8][r]);
}

// ---------------------------------------------------------------------------
// Stage one 64-key K/V tile into an LDS buffer via global_load_lds (16B).
// Per wave: 4 GLDS for K (16 rows x 256B) + 4 GLDS for V (32 d-rows x 128B).
// Global layouts are pre-swizzled, LDS destinations are linear (rule 21).
// ---------------------------------------------------------------------------
static __device__ __forceinline__ void stage_kv(
    const short* Kb, const short* Vb, short* buf, int key0, int w, int lane) {
#pragma unroll
  for (int i = 0; i < 4; ++i)
    GLDS16(Kb + ((size_t)key0 + w * 16 + i * 4) * 128 + lane * 8,
           buf + (w * 16 + i * 4) * 128);
#pragma unroll
  for (int j = 0; j < 4; ++j)
    GLDS16(Vb + (size_t)(w * 32 + j * 8 + (lane >> 3)) * 4096 + key0 +
               (lane & 7) * 8,
           buf + 8192 + (w * 32 + j * 8) * 64);
}

// ---------------------------------------------------------------------------
// Lyra attention, bf16 MFMA, NO K-split: one block per (qt, hj) handles all
// 4096 keys, normalizes in-block (fixed-max softmax partials are plain sums;
// row-sum via ones-fragment MFMA) and writes combined_bf directly.
// Pipeline: triple-buffered LDS K/V tiles staged by global_load_lds, ONE raw
// s_barrier per tile, counted s_waitcnt vmcnt(8) (never drained in-loop).
// Grid (hj=8, qt=32): linear id % 8 == hj -> each XCD caches exactly one
// kvh's K+V (2 MB) in its 4 MB L2.
// ---------------------------------------------------------------------------
__global__ __launch_bounds__(256) void lyra_attn(
    const float* __restrict__ qkv,
    const short* __restrict__ Kbf,   // [4][4096][128] pre-swizzled rows
    const short* __restrict__ Vtb,   // [4][128][4096] pre-swizzled 64-chunks
    short* __restrict__ combined_bf) {
  __shared__ short sKV[3][16384];    // per buf: [0..8191]=K(key*128+e), [8192..]=Vt(d*64+e)
  __shared__ short sP[4][16][72];    // per-wave P tile (no cross-wave use)
  const int hj = blockIdx.x;         // 0..7  (low bits -> XCD pin)
  const int qt = blockIdx.y;         // 0..31
  const int kvh = hj >> 1;
  const int t = threadIdx.x;
  const int w = t >> 6;
  const int lane = t & 63;
  const int quad = lane >> 4;
  const int l16 = lane & 15;
  const int row0 = qt * 64;
  const int rbase = row0 + w * 16 + quad * 4;
  const int swx = (l16 & 7) << 4;    // byte XOR for swizzled ds_read_b128

  // q fragments (fp32 global -> bf16 regs)
  bf16x8 qf[4];
  {
    const float* qrow =
        qkv + (size_t)(row0 + w * 16 + l16) * QKV_W + (8 + hj) * DH;
#pragma unroll
    for (int ks = 0; ks < 4; ++ks) {
      float4 f0 = *(const float4*)(qrow + ks * 32 + quad * 8);
      float4 f1 = *(const float4*)(qrow + ks * 32 + quad * 8 + 4);
      qf[ks][0] = f2bf(f0.x); qf[ks][1] = f2bf(f0.y);
      qf[ks][2] = f2bf(f0.z); qf[ks][3] = f2bf(f0.w);
      qf[ks][4] = f2bf(f1.x); qf[ks][5] = f2bf(f1.y);
      qf[ks][6] = f2bf(f1.z); qf[ks][7] = f2bf(f1.w);
    }
  }
  bf16x8 onesf;
#pragma unroll
  for (int i = 0; i < 8; ++i) onesf[i] = (short)0x3F80;  // bf16 1.0

  f32x4 accO[8];
#pragma unroll
  for (int i = 0; i < 8; ++i) accO[i] = (f32x4){0.f, 0.f, 0.f, 0.f};
  f32x4 accL = (f32x4){0.f, 0.f, 0.f, 0.f};

  const short* Kb = Kbf + (size_t)kvh * 4096 * DH;
  const short* Vb = Vtb + (size_t)kvh * DH * 4096;

  // prologue: tiles 0,1 in flight (8 GLDS each per wave)
  stage_kv(Kb, Vb, &sKV[0][0], 0, w, lane);
  stage_kv(Kb, Vb, &sKV[1][0], 64, w, lane);

  int b = 0;
  for (int kt = 0; kt < 64; ++kt) {
    // my tile-kt loads done (8 newest = tile kt+1 still in flight), then sync
    asm volatile("s_waitcnt vmcnt(8)" ::: "memory");
    __builtin_amdgcn_s_barrier();
    __builtin_amdgcn_sched_barrier(0);

    // issue tile kt+2 into buffer (b+2)%3 — distinct from buf b (being read)
    // and buf (b+1)%3 (landing); all waves passed the barrier above, so no
    // wave still reads (b+2)%3 (= tile kt-1's buffer).
    {
      int nb = b + 2; if (nb >= 3) nb -= 3;
      stage_kv(Kb, Vb, &sKV[nb][0], ((kt + 2) & 63) * 64, w, lane);
    }

    const char* Ksc = (const char*)&sKV[b][0];
    const char* Vsc = (const char*)&sKV[b][8192];

    // QK^T: 64 q-rows x 64 keys per block (16 rows per wave)
    f32x4 accS[4];
#pragma unroll
    for (int s = 0; s < 4; ++s) accS[s] = (f32x4){0.f, 0.f, 0.f, 0.f};
#pragma unroll
    for (int s = 0; s < 4; ++s) {
      const char* krow = Ksc + (s * 16 + l16) * 256;
#pragma unroll
      for (int ks = 0; ks < 4; ++ks) {
        bf16x8 bk = *(const bf16x8*)(krow + ((ks * 64 + quad * 16) ^ swx));
        accS[s] = __builtin_amdgcn_mfma_f32_16x16x32_bf16(qf[ks], bk, accS[s],
                                                          0, 0, 0);
      }
    }

    // fixed-max softmax: p = exp(s - 12); mask (+1.0) only for keys >= 2048
    const int base = kt * 64;
    if (kt >= 32) {
#pragma unroll
      for (int s = 0; s < 4; ++s) {
        const int col = base + s * 16 + l16;
#pragma unroll
        for (int r = 0; r < 4; ++r) {
          float sc = accS[s][r] * SCALE;
          if ((col - CACHE_LEN) > (rbase + r)) sc += 1.0f;
          sP[w][quad * 4 + r][s * 16 + l16] = f2bf(__expf(sc - LYRA_C));
        }
      }
    } else {
#pragma unroll
      for (int s = 0; s < 4; ++s)
#pragma unroll
        for (int r = 0; r < 4; ++r)
          sP[w][quad * 4 + r][s * 16 + l16] =
              f2bf(__expf(accS[s][r] * SCALE - LYRA_C));
    }

    // PV + row-sum (ones-fragment MFMA); same-wave LDS dependency only
#pragma unroll
    for (int ks = 0; ks < 2; ++ks) {
      bf16x8 ap = *(const bf16x8*)&sP[w][l16][ks * 32 + quad * 8];
      accL = __builtin_amdgcn_mfma_f32_16x16x32_bf16(ap, onesf, accL, 0, 0, 0);
#pragma unroll
      for (int t8 = 0; t8 < 8; ++t8) {
        const char* vrow = Vsc + (t8 * 16 + l16) * 128;
        bf16x8 bv = *(const bf16x8*)(vrow + ((ks * 64 + quad * 16) ^ swx));
        accO[t8] = __builtin_amdgcn_mfma_f32_16x16x32_bf16(ap, bv, accO[t8],
                                                           0, 0, 0);
      }
    }

    ++b; if (b == 3) b = 0;
  }

  // epilogue: normalize (accL[r] holds the full 4096-key row sum in every
  // lane — ones-B makes all C columns equal) and write bf16 output directly.
  float inv[4];
#pragma unroll
  for (int r = 0; r < 4; ++r) inv[r] = 1.0f / accL[r];
#pragma unroll
  for (int t8 = 0; t8 < 8; ++t8)
#pragma unroll
    for (int r = 0; r < 4; ++r)
      combined_bf[(size_t)(rbase + r) * HID + (8 + hj) * DH + t8 * 16 + l16] =
          f2bf(accO[t8][r] * inv[r]);
}

// ---------------------------------------------------------------------------
extern "C" void kernel_launch(void* const* d_in, const int* in_sizes, int n_in,
                              void* d_out, int out_size, void* d_ws, size_t ws_size,
                              hipStream_t stream) {
  (void)in_sizes; (void)n_in; (void)out_size; (void)ws_size;
  const float* hidden = (const float*)d_in[0];
  const float* cosb   = (const float*)d_in[1];
  const float* sinb   = (const float*)d_in[2];
  const float* kcache = (const float*)d_in[4];
  const float* vcache = (const float*)d_in[5];
  const float* Wq = (const float*)d_in[6];
  const float* Wk = (const float*)d_in[7];
  const float* Wv = (const float*)d_in[8];
  const float* Wo = (const float*)d_in[9];
  const float* qw = (const float*)d_in[10];
  const float* kw = (const float*)d_in[11];

  float* out  = (float*)d_out;                     // attn_output [2048*2048]
  float* wout = out + (size_t)4194304;             // vanilla_w   [8*2048*2048]

  // d_ws: qkv f32 | Kbf | Vtb | combined_bf | Wo_bf
  float* qkv = (float*)d_ws;                       // [2048 x 3072] f32
  short* Kbf = (short*)(qkv + (size_t)2048 * QKV_W);
  short* Vtb = Kbf + (size_t)4 * 4096 * DH;
  short* combined_bf = Vtb + (size_t)4 * DH * 4096;   // [2048 x 2048] bf16
  short* Wo_bf = combined_bf + (size_t)2048 * HID;    // [2048 x 2048] bf16

  // transient scratch inside wout (consumed before vscore overwrites):
  short* hidden_bf = (short*)wout;                    // [2048 x 2048] bf16
  short* Wqkv_bf = hidden_bf + (size_t)2048 * HID;    // [3072 x 2048] bf16

  pack_bf16<<<dim3(2048), 256, 0, stream>>>(hidden, hidden_bf);
  pack_bf16<<<dim3(2048), 256, 0, stream>>>(Wq, Wqkv_bf);
  pack_bf16<<<dim3(512), 256, 0, stream>>>(Wk, Wqkv_bf + (size_t)2048 * 2048);
  pack_bf16<<<dim3(512), 256, 0, stream>>>(Wv, Wqkv_bf + (size_t)2560 * 2048);
  pack_bf16<<<dim3(2048), 256, 0, stream>>>(Wo, Wo_bf);

  gemm_bf16<<<dim3(24, 16), 256, 0, stream>>>(hidden_bf, Wqkv_bf, qkv, 2048, QKV_W);
  rms_rope<<<dim3(10240), 256, 0, stream>>>(qkv, cosb, sinb, qw, kw);
  pack_k<<<dim3(2048), 256, 0, stream>>>(qkv, kcache, Kbf);
  pack_vt<<<dim3(64, 2, 4), 256, 0, stream>>>(qkv, vcache, Vtb);
  lyra_attn<<<dim3(8, 32), 256, 0, stream>>>(qkv, Kbf, Vtb, combined_bf);
  vscore_gemm<<<dim3(16, 16, 8), 256, 0, stream>>>(qkv, wout);
  vsoftmax<<<dim3(2048, 8), 256, 0, stream>>>(wout);
  vout_mfma<<<dim3(128, 8), 64, 0, stream>>>(wout, Vtb, combined_bf);
  gemm_bf16<<<dim3(16, 16), 256, 0, stream>>>(combined_bf, Wo_bf, out, 2048, HID);
}

// Round 2
// 579.359 us; speedup vs baseline: 1.1806x; 1.0278x over previous
//
#include <hip/hip_runtime.h>
#include <math.h>

#define S_LEN 2048
#define HID 2048
#define NH 16
#define NKV 4
#define DH 128
#define CACHE_LEN 2048
#define QKV_W 3072   // q(2048) | k(512) | v(512) packed per row
#define SCALE 0.08838834764831845f
#define EPS 1e-6f
#define LYRA_C 12.0f // fixed softmax max-bound: |scores| <= ~19, exp(s-12) safe

typedef short bf16x8 __attribute__((ext_vector_type(8)));
typedef float f32x4 __attribute__((ext_vector_type(4)));

static __device__ __forceinline__ short f2bf(float x) {
  union { float f; unsigned u; } v; v.f = x;
  unsigned r = (v.u + 0x7FFF + ((v.u >> 16) & 1)) >> 16;
  return (short)r;
}

#define GLDS16(g, l)                                                      \
  __builtin_amdgcn_global_load_lds(                                       \
      (const __attribute__((address_space(1))) unsigned int*)(g),         \
      (__attribute__((address_space(3))) unsigned int*)(l), 16, 0, 0)

// ---------------------------------------------------------------------------
// fp32 -> bf16 pack, 8 elements/thread.
// ---------------------------------------------------------------------------
__global__ __launch_bounds__(256) void pack_bf16(
    const float* __restrict__ src, short* __restrict__ dst) {
  const int i = (blockIdx.x * 256 + threadIdx.x) * 8;
  float4 a = *(const float4*)(src + i);
  float4 b = *(const float4*)(src + i + 4);
  bf16x8 o;
  o[0] = f2bf(a.x); o[1] = f2bf(a.y); o[2] = f2bf(a.z); o[3] = f2bf(a.w);
  o[4] = f2bf(b.x); o[5] = f2bf(b.y); o[6] = f2bf(b.z); o[7] = f2bf(b.w);
  *(bf16x8*)(dst + i) = o;
}

// ---------------------------------------------------------------------------
// bf16 MFMA GEMM: C[M x N] fp32 = A[M x K]bf16 * B[N x K]bf16^T.
// ---------------------------------------------------------------------------
__global__ __launch_bounds__(256) void gemm_bf16(
    const short* __restrict__ A, const short* __restrict__ B,
    float* __restrict__ C, int K, int ldc) {
  __shared__ short sA[4096];
  __shared__ short sB[4096];
  const int t = threadIdx.x;
  const int w = t >> 6;
  const int lane = t & 63;
  const int quad = lane >> 4;
  const int l16 = lane & 15;
  const int tm = blockIdx.y * 128;
  const int tn = blockIdx.x * 128;
  const int srow = lane >> 2;
  const int scol = (lane & 3) * 8;
  const int mblk = (w & 1) * 64;
  const int nblk = (w >> 1) * 64;
  f32x4 acc[4][4];
#pragma unroll
  for (int i = 0; i < 4; ++i)
#pragma unroll
    for (int j = 0; j < 4; ++j) acc[i][j] = (f32x4){0.f, 0.f, 0.f, 0.f};

  const short* Ab = A + (size_t)(tm + w * 32 + srow) * K + scol;
  const short* Bb = B + (size_t)(tn + w * 32 + srow) * K + scol;
  const size_t rstep = (size_t)16 * K;

  for (int k0 = 0; k0 < K; k0 += 32) {
    GLDS16(Ab + k0, sA + (w * 2 + 0) * 512);
    GLDS16(Ab + rstep + k0, sA + (w * 2 + 1) * 512);
    GLDS16(Bb + k0, sB + (w * 2 + 0) * 512);
    GLDS16(Bb + rstep + k0, sB + (w * 2 + 1) * 512);
    __syncthreads();
    bf16x8 af[4], bfv[4];
#pragma unroll
    for (int ms = 0; ms < 4; ++ms)
      af[ms] = *(const bf16x8*)&sA[(mblk + ms * 16 + l16) * 32 + quad * 8];
#pragma unroll
    for (int ns = 0; ns < 4; ++ns)
      bfv[ns] = *(const bf16x8*)&sB[(nblk + ns * 16 + l16) * 32 + quad * 8];
#pragma unroll
    for (int ms = 0; ms < 4; ++ms)
#pragma unroll
      for (int ns = 0; ns < 4; ++ns)
        acc[ms][ns] = __builtin_amdgcn_mfma_f32_16x16x32_bf16(
            af[ms], bfv[ns], acc[ms][ns], 0, 0, 0);
    __syncthreads();
  }
#pragma unroll
  for (int ms = 0; ms < 4; ++ms)
#pragma unroll
    for (int ns = 0; ns < 4; ++ns) {
      const int row = tm + mblk + ms * 16 + quad * 4;
      const int col = tn + nblk + ns * 16 + l16;
#pragma unroll
      for (int r = 0; r < 4; ++r)
        C[(size_t)(row + r) * ldc + col] = acc[ms][ns][r];
    }
}

// ---------------------------------------------------------------------------
// RMSNorm(+1+w) then RoPE, in-place on q (16 heads) and k (4 heads).
// ---------------------------------------------------------------------------
__global__ __launch_bounds__(256) void rms_rope(
    float* __restrict__ qkv,
    const float* __restrict__ cosb, const float* __restrict__ sinb,
    const float* __restrict__ qw, const float* __restrict__ kw) {
  const int unit = blockIdx.x * 4 + (threadIdx.x >> 6);
  const int lane = threadIdx.x & 63;
  const int total_q = S_LEN * NH;
  float* base;
  const float* w;
  int pos;
  if (unit < total_q) {
    pos = unit >> 4;
    int head = unit & 15;
    base = qkv + (size_t)pos * QKV_W + head * DH;
    w = qw;
  } else {
    int u = unit - total_q;
    pos = u >> 2;
    int head = u & 3;
    base = qkv + (size_t)pos * QKV_W + 2048 + head * DH;
    w = kw;
  }
  float x0 = base[lane];
  float x1 = base[lane + 64];
  float ss = x0 * x0 + x1 * x1;
#pragma unroll
  for (int off = 32; off > 0; off >>= 1) ss += __shfl_xor(ss, off);
  float r = rsqrtf(ss * (1.0f / 128.0f) + EPS);
  float n0 = x0 * r * (1.0f + w[lane]);
  float n1 = x1 * r * (1.0f + w[lane + 64]);
  float c0 = cosb[(size_t)pos * DH + lane];
  float c1 = cosb[(size_t)pos * DH + lane + 64];
  float s0 = sinb[(size_t)pos * DH + lane];
  float s1 = sinb[(size_t)pos * DH + lane + 64];
  base[lane]      = n0 * c0 - n1 * s0;
  base[lane + 64] = n1 * c1 + n0 * s1;
}

// ---------------------------------------------------------------------------
// Pack K (cache ++ roped k) -> bf16 Kbf[4][4096][128], PRE-SWIZZLED within
// each 128-elem row: element d stored at d ^ ((key&7)<<3).  global_load_lds
// then copies rows linearly and the swizzled ds_read_b128 is conflict-free.
// ---------------------------------------------------------------------------
__global__ __launch_bounds__(256) void pack_k(
    const float* __restrict__ qkv, const float* __restrict__ kcache,
    short* __restrict__ Kbf) {
  const int idx = blockIdx.x * 256 + threadIdx.x;
  const int e4 = idx * 4;
  const int kvh = e4 >> 19;
  const int rem = e4 & ((1 << 19) - 1);
  const int key = rem >> 7;
  const int d = rem & 127;
  float4 v;
  if (key < CACHE_LEN)
    v = *(const float4*)(kcache + (((size_t)kvh * CACHE_LEN + key) << 7) + d);
  else
    v = *(const float4*)(qkv + (size_t)(key - CACHE_LEN) * QKV_W + 2048 + kvh * DH + d);
  short4 o;
  o.x = f2bf(v.x); o.y = f2bf(v.y); o.z = f2bf(v.z); o.w = f2bf(v.w);
  const int dsw = d ^ ((key & 7) << 3);       // in-row XOR swizzle (8-elem units)
  *(short4*)(Kbf + (size_t)(e4 - d) + dsw) = o;
}

// ---------------------------------------------------------------------------
// Pack V transposed -> bf16 Vt[4][128][4096], PRE-SWIZZLED within each
// 64-key chunk: key c stored at c ^ ((d&7)<<3).
// ---------------------------------------------------------------------------
__global__ __launch_bounds__(256) void pack_vt(
    const float* __restrict__ qkv, const float* __restrict__ vcache,
    short* __restrict__ Vt) {
  __shared__ float tile[64][65];
  const int key0 = blockIdx.x * 64;
  const int d0 = blockIdx.y * 64;
  const int kvh = blockIdx.z;
  const int t = threadIdx.x;
  const int c = t & 63;
  const int r0 = t >> 6;
#pragma unroll
  for (int i = 0; i < 16; ++i) {
    int r = r0 + i * 4;
    int key = key0 + r;
    float v;
    if (key < CACHE_LEN)
      v = vcache[(((size_t)kvh * CACHE_LEN + key) << 7) + d0 + c];
    else
      v = qkv[(size_t)(key - CACHE_LEN) * QKV_W + 2560 + kvh * DH + d0 + c];
    tile[r][c] = v;
  }
  __syncthreads();
#pragma unroll
  for (int i = 0; i < 16; ++i) {
    int wr = r0 + i * 4;
    int csw = c ^ (((d0 + wr) & 7) << 3);     // in-chunk XOR swizzle
    Vt[((size_t)kvh * DH + d0 + wr) * 4096 + key0 + csw] = f2bf(tile[c][wr]);
  }
}

// ---------------------------------------------------------------------------
// Vanilla scores (causal) — fp32 (output 1 accuracy)
// ---------------------------------------------------------------------------
__global__ __launch_bounds__(256) void vscore_gemm(
    const float* __restrict__ qkv, float* __restrict__ wout) {
  const int bx = blockIdx.x, by = blockIdx.y, h = blockIdx.z;
  if (bx > by) return;
  __shared__ float As[8][132];
  __shared__ float Bs[8][132];
  const int t = threadIdx.x;
  const int lr = t >> 1;
  const int lc = (t & 1) * 4;
  const float* Ap = qkv + h * DH + (size_t)(by * 128 + lr) * QKV_W + lc;
  const float* Bp = qkv + 2048 + (h >> 1) * DH + (size_t)(bx * 128 + lr) * QKV_W + lc;
  const int tx = t & 15;
  const int ty = t >> 4;
  float acc[8][8];
#pragma unroll
  for (int i = 0; i < 8; ++i)
#pragma unroll
    for (int j = 0; j < 8; ++j) acc[i][j] = 0.f;
  for (int k0 = 0; k0 < DH; k0 += 8) {
    float4 av = *(const float4*)(Ap + k0);
    float4 bv = *(const float4*)(Bp + k0);
    __syncthreads();
    As[lc + 0][lr] = av.x; As[lc + 1][lr] = av.y;
    As[lc + 2][lr] = av.z; As[lc + 3][lr] = av.w;
    Bs[lc + 0][lr] = bv.x; Bs[lc + 1][lr] = bv.y;
    Bs[lc + 2][lr] = bv.z; Bs[lc + 3][lr] = bv.w;
    __syncthreads();
#pragma unroll
    for (int k = 0; k < 8; ++k) {
      float4 a0 = *(const float4*)&As[k][ty * 4];
      float4 a1 = *(const float4*)&As[k][64 + ty * 4];
      float4 b0 = *(const float4*)&Bs[k][tx * 4];
      float4 b1 = *(const float4*)&Bs[k][64 + tx * 4];
      float ar[8] = {a0.x, a0.y, a0.z, a0.w, a1.x, a1.y, a1.z, a1.w};
      float br[8] = {b0.x, b0.y, b0.z, b0.w, b1.x, b1.y, b1.z, b1.w};
#pragma unroll
      for (int i = 0; i < 8; ++i)
#pragma unroll
        for (int j = 0; j < 8; ++j)
          acc[i][j] = fmaf(ar[i], br[j], acc[i][j]);
    }
  }
  float* Ch = wout + (size_t)h * S_LEN * S_LEN;
#pragma unroll
  for (int ih = 0; ih < 2; ++ih)
#pragma unroll
    for (int i = 0; i < 4; ++i) {
      int row = by * 128 + ih * 64 + ty * 4 + i;
      int ai = ih * 4 + i;
      float* Crow = Ch + (size_t)row * S_LEN + bx * 128;
      *(float4*)(Crow + tx * 4) =
          make_float4(acc[ai][0] * SCALE, acc[ai][1] * SCALE,
                      acc[ai][2] * SCALE, acc[ai][3] * SCALE);
      *(float4*)(Crow + 64 + tx * 4) =
          make_float4(acc[ai][4] * SCALE, acc[ai][5] * SCALE,
                      acc[ai][6] * SCALE, acc[ai][7] * SCALE);
    }
}

// ---------------------------------------------------------------------------
// Row softmax over s[0..row]; zeros for j>row.
// ---------------------------------------------------------------------------
__global__ __launch_bounds__(256) void vsoftmax(float* __restrict__ wout) {
  const int row = blockIdx.x;
  const int h = blockIdx.y;
  float* p = wout + (size_t)h * S_LEN * S_LEN + (size_t)row * S_LEN;
  const int n = row + 1;
  const int t = threadIdx.x;
  const int lane = t & 63, wid = t >> 6;
  __shared__ float red[4];
  float x[8];
#pragma unroll
  for (int i = 0; i < 8; ++i) {
    int j = t + i * 256;
    x[i] = (j < n) ? p[j] : -INFINITY;
  }
  float m = -INFINITY;
#pragma unroll
  for (int i = 0; i < 8; ++i) m = fmaxf(m, x[i]);
#pragma unroll
  for (int off = 32; off > 0; off >>= 1) m = fmaxf(m, __shfl_xor(m, off));
  if (lane == 0) red[wid] = m;
  __syncthreads();
  m = fmaxf(fmaxf(red[0], red[1]), fmaxf(red[2], red[3]));
  __syncthreads();
  float l = 0.f;
#pragma unroll
  for (int i = 0; i < 8; ++i) {
    x[i] = expf(x[i] - m);
    l += x[i];
  }
#pragma unroll
  for (int off = 32; off > 0; off >>= 1) l += __shfl_xor(l, off);
  if (lane == 0) red[wid] = l;
  __syncthreads();
  l = (red[0] + red[1]) + (red[2] + red[3]);
  const float inv = 1.0f / l;
#pragma unroll
  for (int i = 0; i < 8; ++i) {
    int j = t + i * 256;
    if (j < n) p[j] = x[i] * inv;
  }
  for (int j = n + t; j < S_LEN; j += 256) p[j] = 0.f;
}

// ---------------------------------------------------------------------------
// Vanilla output via bf16 MFMA: O[h][rows 16] = P[16 x kend] * V[kend x 128].
// V reads apply the pack_vt in-chunk XOR swizzle.
// ---------------------------------------------------------------------------
__global__ __launch_bounds__(64) void vout_mfma(
    const float* __restrict__ wout, const short* __restrict__ Vtb,
    short* __restrict__ combined_bf) {
  const int qt = blockIdx.x;   // 0..127
  const int h = blockIdx.y;    // 0..7
  const int kvh = h >> 1;
  const int lane = threadIdx.x;
  const int quad = lane >> 4;
  const int l16 = lane & 15;
  const int row0 = qt * 16;
  const int swx = (l16 & 7) << 3;   // element-index XOR (d&7 == l16&7)
  const float* Wr =
      wout + (size_t)h * S_LEN * S_LEN + (size_t)(row0 + l16) * S_LEN + quad * 8;
  const short* Vb = Vtb + (size_t)kvh * DH * 4096 + 2048;  // current-v keys
  f32x4 acc[8];
#pragma unroll
  for (int i = 0; i < 8; ++i) acc[i] = (f32x4){0.f, 0.f, 0.f, 0.f};
  const int kend = row0 + 16;
  for (int k0 = 0; k0 < kend; k0 += 32) {
    float4 a0 = *(const float4*)(Wr + k0);
    float4 a1 = *(const float4*)(Wr + k0 + 4);
    bf16x8 af;
    af[0] = f2bf(a0.x); af[1] = f2bf(a0.y); af[2] = f2bf(a0.z); af[3] = f2bf(a0.w);
    af[4] = f2bf(a1.x); af[5] = f2bf(a1.y); af[6] = f2bf(a1.z); af[7] = f2bf(a1.w);
#pragma unroll
    for (int t8 = 0; t8 < 8; ++t8) {
      bf16x8 bv = *(const bf16x8*)(
          Vb + (size_t)(t8 * 16 + l16) * 4096 + ((k0 + quad * 8) ^ swx));
      acc[t8] = __builtin_amdgcn_mfma_f32_16x16x32_bf16(af, bv, acc[t8], 0, 0, 0);
    }
  }
  const int rbase = row0 + quad * 4;
#pragma unroll
  for (int t8 = 0; t8 < 8; ++t8)
#pragma unroll
    for (int r = 0; r < 4; ++r)
      combined_bf[(size_t)(rbase + r) * HID + h * DH + t8 * 16 + l16] =
          f2bf(acc[t8][r]);
}

// ---------------------------------------------------------------------------
// Stage one 64-key K/V tile into an LDS buffer via global_load_lds (16B).
// 8 waves: per wave 2 GLDS for K (8 key-rows x 256B) + 2 GLDS for V
// (16 d-rows x 128B).  Global layouts are pre-swizzled, LDS dests linear.
// ---------------------------------------------------------------------------
static __device__ __forceinline__ void stage_kv(
    const short* Kb, const short* Vb, short* buf, int key0, int w, int lane) {
#pragma unroll
  for (int i = 0; i < 2; ++i)
    GLDS16(Kb + ((size_t)key0 + w * 8 + i * 4) * 128 + lane * 8,
           buf + (w * 8 + i * 4) * 128);
#pragma unroll
  for (int j = 0; j < 2; ++j)
    GLDS16(Vb + (size_t)(w * 16 + j * 8 + (lane >> 3)) * 4096 + key0 +
               (lane & 7) * 8,
           buf + 8192 + (w * 16 + j * 8) * 64);
}

// ---------------------------------------------------------------------------
// Lyra attention: 8 waves = 4 row-waves x 2 key-column-waves -> 2 waves/SIMD
// for latency hiding at unchanged per-CU work.  Wave (wr,wc) computes
// S[16 rows][32 keys] and accumulates O/L partials over its 32-key slice;
// partials merged once at the epilogue through LDS (K/V buffer reused).
// Triple-buffered K/V staging via global_load_lds, one s_barrier per tile,
// counted s_waitcnt vmcnt(4).  sP per-wave [16][64] (128B rows) with
// slot ^= row&7 XOR on write and read (conflict-free ds_read_b128).
// Grid (hj=8, qt=32): id%8 == hj pins each kvh's K+V (2MB) to one XCD L2.
// ---------------------------------------------------------------------------
__global__ __launch_bounds__(512) void lyra_attn(
    const float* __restrict__ qkv,
    const short* __restrict__ Kbf,   // [4][4096][128] pre-swizzled rows
    const short* __restrict__ Vtb,   // [4][128][4096] pre-swizzled 64-chunks
    short* __restrict__ combined_bf) {
  __shared__ short sKV[3][16384];    // per buf: [0..8191]=K(key*128+e), [8192..]=Vt(d*64+e)
  __shared__ short sP[8][16][64];    // per-wave P tile, slot-XOR swizzled
  __shared__ float sL[64];
  const int hj = blockIdx.x;         // 0..7  (low bits -> XCD pin)
  const int qt = blockIdx.y;         // 0..31
  const int kvh = hj >> 1;
  const int t = threadIdx.x;
  const int w = t >> 6;              // 0..7
  const int lane = t & 63;
  const int quad = lane >> 4;
  const int l16 = lane & 15;
  const int wr = w >> 1;             // row-wave 0..3 (16 rows each)
  const int wc = w & 1;              // key-wave 0..1 (32 keys each)
  const int row0 = qt * 64;
  const int rbase = row0 + wr * 16 + quad * 4;
  const int swx = (l16 & 7) << 4;    // byte XOR for swizzled ds_read_b128

  // q fragments (fp32 global -> bf16 regs), rows wr*16+l16, full 128 dims
  bf16x8 qf[4];
  {
    const float* qrow =
        qkv + (size_t)(row0 + wr * 16 + l16) * QKV_W + (8 + hj) * DH;
#pragma unroll
    for (int ks = 0; ks < 4; ++ks) {
      float4 f0 = *(const float4*)(qrow + ks * 32 + quad * 8);
      float4 f1 = *(const float4*)(qrow + ks * 32 + quad * 8 + 4);
      qf[ks][0] = f2bf(f0.x); qf[ks][1] = f2bf(f0.y);
      qf[ks][2] = f2bf(f0.z); qf[ks][3] = f2bf(f0.w);
      qf[ks][4] = f2bf(f1.x); qf[ks][5] = f2bf(f1.y);
      qf[ks][6] = f2bf(f1.z); qf[ks][7] = f2bf(f1.w);
    }
  }
  bf16x8 onesf;
#pragma unroll
  for (int i = 0; i < 8; ++i) onesf[i] = (short)0x3F80;  // bf16 1.0

  f32x4 accO[8];
#pragma unroll
  for (int i = 0; i < 8; ++i) accO[i] = (f32x4){0.f, 0.f, 0.f, 0.f};
  f32x4 accL = (f32x4){0.f, 0.f, 0.f, 0.f};

  const short* Kb = Kbf + (size_t)kvh * 4096 * DH;
  const short* Vb = Vtb + (size_t)kvh * DH * 4096;

  // prologue: tiles 0,1 in flight (4 GLDS each per wave)
  stage_kv(Kb, Vb, &sKV[0][0], 0, w, lane);
  stage_kv(Kb, Vb, &sKV[1][0], 64, w, lane);

  short* sPw = &sP[w][0][0];
  int b = 0;
  for (int kt = 0; kt < 64; ++kt) {
    // my tile-kt loads done (4 newest = tile kt+1 still in flight), then sync
    asm volatile("s_waitcnt vmcnt(4)" ::: "memory");
    __builtin_amdgcn_s_barrier();
    __builtin_amdgcn_sched_barrier(0);

    // issue tile kt+2 into buffer (b+2)%3 (tile kt-1's buffer, fully read)
    {
      int nb = b + 2; if (nb >= 3) nb -= 3;
      stage_kv(Kb, Vb, &sKV[nb][0], ((kt + 2) & 63) * 64, w, lane);
    }

    const char* Ksc = (const char*)&sKV[b][0];
    const char* Vsc = (const char*)&sKV[b][8192];

    // QK^T: 16 rows (wr) x 32 keys (wc-slice)
    f32x4 accS[2];
#pragma unroll
    for (int s = 0; s < 2; ++s) accS[s] = (f32x4){0.f, 0.f, 0.f, 0.f};
    __builtin_amdgcn_s_setprio(1);
#pragma unroll
    for (int s = 0; s < 2; ++s) {
      const char* krow = Ksc + (wc * 32 + s * 16 + l16) * 256;
#pragma unroll
      for (int ks = 0; ks < 4; ++ks) {
        bf16x8 bk = *(const bf16x8*)(krow + ((ks * 64 + quad * 16) ^ swx));
        accS[s] = __builtin_amdgcn_mfma_f32_16x16x32_bf16(qf[ks], bk, accS[s],
                                                          0, 0, 0);
      }
    }
    __builtin_amdgcn_s_setprio(0);

    // fixed-max softmax: p = exp(s - 12); mask (+1.0) only for keys >= 2048.
    // sP store position: row = quad*4+r, key2 = s*16+l16;
    // slot = key2>>3, swizzled slot' = slot ^ (row&7).
    const int base = kt * 64 + wc * 32;
    if (kt >= 32) {
#pragma unroll
      for (int s = 0; s < 2; ++s) {
        const int col = base + s * 16 + l16;
#pragma unroll
        for (int r = 0; r < 4; ++r) {
          const int row = quad * 4 + r;
          float sc = accS[s][r] * SCALE;
          if ((col - CACHE_LEN) > (rbase + r)) sc += 1.0f;
          const int sl = (s * 2 + (l16 >> 3)) ^ (row & 7);
          sPw[row * 64 + sl * 8 + (l16 & 7)] = f2bf(__expf(sc - LYRA_C));
        }
      }
    } else {
#pragma unroll
      for (int s = 0; s < 2; ++s)
#pragma unroll
        for (int r = 0; r < 4; ++r) {
          const int row = quad * 4 + r;
          const int sl = (s * 2 + (l16 >> 3)) ^ (row & 7);
          sPw[row * 64 + sl * 8 + (l16 & 7)] =
              f2bf(__expf(accS[s][r] * SCALE - LYRA_C));
        }
    }

    // PV + row-sum over this wave's 32-key slice (K=32 -> one fragment)
    __builtin_amdgcn_s_setprio(1);
    bf16x8 ap = *(const bf16x8*)&sPw[l16 * 64 + ((quad ^ (l16 & 7)) << 3)];
    accL = __builtin_amdgcn_mfma_f32_16x16x32_bf16(ap, onesf, accL, 0, 0, 0);
#pragma unroll
    for (int t8 = 0; t8 < 8; ++t8) {
      bf16x8 bv = *(const bf16x8*)(
          Vsc + (t8 * 16 + l16) * 128 + ((wc * 64 + quad * 16) ^ swx));
      accO[t8] = __builtin_amdgcn_mfma_f32_16x16x32_bf16(ap, bv, accO[t8],
                                                         0, 0, 0);
    }
    __builtin_amdgcn_s_setprio(0);

    ++b; if (b == 3) b = 0;
  }

  // epilogue: merge wc partials through LDS (reuse K/V buffer 0 — last tile
  // (63) lived in buffer 0 and is fully read; in-flight GLDS target bufs 1,2),
  // normalize, write bf16 output.
  __syncthreads();
  float* sO = (float*)&sKV[0][0];    // [64 rows][128] f32 = 32 KB
  if (wc == 1) {
#pragma unroll
    for (int t8 = 0; t8 < 8; ++t8)
#pragma unroll
      for (int r = 0; r < 4; ++r)
        sO[((wr * 16 + quad * 4 + r) << 7) + t8 * 16 + l16] = accO[t8][r];
    if (l16 == 0) {
#pragma unroll
      for (int r = 0; r < 4; ++r) sL[wr * 16 + quad * 4 + r] = accL[r];
    }
  }
  __syncthreads();
  if (wc == 0) {
    float linv[4];
#pragma unroll
    for (int r = 0; r < 4; ++r)
      linv[r] = 1.0f / (accL[r] + sL[wr * 16 + quad * 4 + r]);
#pragma unroll
    for (int t8 = 0; t8 < 8; ++t8)
#pragma unroll
      for (int r = 0; r < 4; ++r) {
        float o = accO[t8][r] + sO[((wr * 16 + quad * 4 + r) << 7) + t8 * 16 + l16];
        combined_bf[(size_t)(rbase + r) * HID + (8 + hj) * DH + t8 * 16 + l16] =
            f2bf(o * linv[r]);
      }
  }
}

// ---------------------------------------------------------------------------
extern "C" void kernel_launch(void* const* d_in, const int* in_sizes, int n_in,
                              void* d_out, int out_size, void* d_ws, size_t ws_size,
                              hipStream_t stream) {
  (void)in_sizes; (void)n_in; (void)out_size; (void)ws_size;
  const float* hidden = (const float*)d_in[0];
  const float* cosb   = (const float*)d_in[1];
  const float* sinb   = (const float*)d_in[2];
  const float* kcache = (const float*)d_in[4];
  const float* vcache = (const float*)d_in[5];
  const float* Wq = (const float*)d_in[6];
  const float* Wk = (const float*)d_in[7];
  const float* Wv = (const float*)d_in[8];
  const float* Wo = (const float*)d_in[9];
  const float* qw = (const float*)d_in[10];
  const float* kw = (const float*)d_in[11];

  float* out  = (float*)d_out;                     // attn_output [2048*2048]
  float* wout = out + (size_t)4194304;             // vanilla_w   [8*2048*2048]

  // d_ws: qkv f32 | Kbf | Vtb | combined_bf | Wo_bf
  float* qkv = (float*)d_ws;                       // [2048 x 3072] f32
  short* Kbf = (short*)(qkv + (size_t)2048 * QKV_W);
  short* Vtb = Kbf + (size_t)4 * 4096 * DH;
  short* combined_bf = Vtb + (size_t)4 * DH * 4096;   // [2048 x 2048] bf16
  short* Wo_bf = combined_bf + (size_t)2048 * HID;    // [2048 x 2048] bf16

  // transient scratch inside wout (consumed before vscore overwrites):
  short* hidden_bf = (short*)wout;                    // [2048 x 2048] bf16
  short* Wqkv_bf = hidden_bf + (size_t)2048 * HID;    // [3072 x 2048] bf16

  pack_bf16<<<dim3(2048), 256, 0, stream>>>(hidden, hidden_bf);
  pack_bf16<<<dim3(2048), 256, 0, stream>>>(Wq, Wqkv_bf);
  pack_bf16<<<dim3(512), 256, 0, stream>>>(Wk, Wqkv_bf + (size_t)2048 * 2048);
  pack_bf16<<<dim3(512), 256, 0, stream>>>(Wv, Wqkv_bf + (size_t)2560 * 2048);
  pack_bf16<<<dim3(2048), 256, 0, stream>>>(Wo, Wo_bf);

  gemm_bf16<<<dim3(24, 16), 256, 0, stream>>>(hidden_bf, Wqkv_bf, qkv, 2048, QKV_W);
  rms_rope<<<dim3(10240), 256, 0, stream>>>(qkv, cosb, sinb, qw, kw);
  pack_k<<<dim3(2048), 256, 0, stream>>>(qkv, kcache, Kbf);
  pack_vt<<<dim3(64, 2, 4), 256, 0, stream>>>(qkv, vcache, Vtb);
  lyra_attn<<<dim3(8, 32), 512, 0, stream>>>(qkv, Kbf, Vtb, combined_bf);
  vscore_gemm<<<dim3(16, 16, 8), 256, 0, stream>>>(qkv, wout);
  vsoftmax<<<dim3(2048, 8), 256, 0, stream>>>(wout);
  vout_mfma<<<dim3(128, 8), 64, 0, stream>>>(wout, Vtb, combined_bf);
  gemm_bf16<<<dim3(16, 16), 256, 0, stream>>>(combined_bf, Wo_bf, out, 2048, HID);
}

// Round 3
// 513.010 us; speedup vs baseline: 1.3333x; 1.1293x over previous
//
#include <hip/hip_runtime.h>
#include <math.h>

#define S_LEN 2048
#define HID 2048
#define NH 16
#define NKV 4
#define DH 128
#define CACHE_LEN 2048
#define QKV_W 3072   // q(2048) | k(512) | v(512) packed per row
#define SCALE 0.08838834764831845f
#define EPS 1e-6f
#define LYRA_C 12.0f // fixed softmax max-bound: |scores| <= ~19, exp(s-12) safe

typedef short bf16x8 __attribute__((ext_vector_type(8)));
typedef float f32x4 __attribute__((ext_vector_type(4)));

static __device__ __forceinline__ short f2bf(float x) {
  union { float f; unsigned u; } v; v.f = x;
  unsigned r = (v.u + 0x7FFF + ((v.u >> 16) & 1)) >> 16;
  return (short)r;
}

static __device__ __forceinline__ float bf2f(short h) {
  union { unsigned u; float f; } v;
  v.u = ((unsigned)(unsigned short)h) << 16;
  return v.f;
}

#define GLDS16(g, l)                                                      \
  __builtin_amdgcn_global_load_lds(                                       \
      (const __attribute__((address_space(1))) unsigned int*)(g),         \
      (__attribute__((address_space(3))) unsigned int*)(l), 16, 0, 0)

// ---------------------------------------------------------------------------
// fp32 -> bf16 pack, 8 elements/thread.
// ---------------------------------------------------------------------------
__global__ __launch_bounds__(256) void pack_bf16(
    const float* __restrict__ src, short* __restrict__ dst) {
  const int i = (blockIdx.x * 256 + threadIdx.x) * 8;
  float4 a = *(const float4*)(src + i);
  float4 b = *(const float4*)(src + i + 4);
  bf16x8 o;
  o[0] = f2bf(a.x); o[1] = f2bf(a.y); o[2] = f2bf(a.z); o[3] = f2bf(a.w);
  o[4] = f2bf(b.x); o[5] = f2bf(b.y); o[6] = f2bf(b.z); o[7] = f2bf(b.w);
  *(bf16x8*)(dst + i) = o;
}

// ---------------------------------------------------------------------------
// bf16 MFMA GEMM: C[M x N] fp32 = A[M x K]bf16 * B[N x K]bf16^T.
// ---------------------------------------------------------------------------
__global__ __launch_bounds__(256) void gemm_bf16(
    const short* __restrict__ A, const short* __restrict__ B,
    float* __restrict__ C, int K, int ldc) {
  __shared__ short sA[4096];
  __shared__ short sB[4096];
  const int t = threadIdx.x;
  const int w = t >> 6;
  const int lane = t & 63;
  const int quad = lane >> 4;
  const int l16 = lane & 15;
  const int tm = blockIdx.y * 128;
  const int tn = blockIdx.x * 128;
  const int srow = lane >> 2;
  const int scol = (lane & 3) * 8;
  const int mblk = (w & 1) * 64;
  const int nblk = (w >> 1) * 64;
  f32x4 acc[4][4];
#pragma unroll
  for (int i = 0; i < 4; ++i)
#pragma unroll
    for (int j = 0; j < 4; ++j) acc[i][j] = (f32x4){0.f, 0.f, 0.f, 0.f};

  const short* Ab = A + (size_t)(tm + w * 32 + srow) * K + scol;
  const short* Bb = B + (size_t)(tn + w * 32 + srow) * K + scol;
  const size_t rstep = (size_t)16 * K;

  for (int k0 = 0; k0 < K; k0 += 32) {
    GLDS16(Ab + k0, sA + (w * 2 + 0) * 512);
    GLDS16(Ab + rstep + k0, sA + (w * 2 + 1) * 512);
    GLDS16(Bb + k0, sB + (w * 2 + 0) * 512);
    GLDS16(Bb + rstep + k0, sB + (w * 2 + 1) * 512);
    __syncthreads();
    bf16x8 af[4], bfv[4];
#pragma unroll
    for (int ms = 0; ms < 4; ++ms)
      af[ms] = *(const bf16x8*)&sA[(mblk + ms * 16 + l16) * 32 + quad * 8];
#pragma unroll
    for (int ns = 0; ns < 4; ++ns)
      bfv[ns] = *(const bf16x8*)&sB[(nblk + ns * 16 + l16) * 32 + quad * 8];
#pragma unroll
    for (int ms = 0; ms < 4; ++ms)
#pragma unroll
      for (int ns = 0; ns < 4; ++ns)
        acc[ms][ns] = __builtin_amdgcn_mfma_f32_16x16x32_bf16(
            af[ms], bfv[ns], acc[ms][ns], 0, 0, 0);
    __syncthreads();
  }
#pragma unroll
  for (int ms = 0; ms < 4; ++ms)
#pragma unroll
    for (int ns = 0; ns < 4; ++ns) {
      const int row = tm + mblk + ms * 16 + quad * 4;
      const int col = tn + nblk + ns * 16 + l16;
#pragma unroll
      for (int r = 0; r < 4; ++r)
        C[(size_t)(row + r) * ldc + col] = acc[ms][ns][r];
    }
}

// ---------------------------------------------------------------------------
// RMSNorm(+1+w) then RoPE, in-place on q (16 heads) and k (4 heads).
// ---------------------------------------------------------------------------
__global__ __launch_bounds__(256) void rms_rope(
    float* __restrict__ qkv,
    const float* __restrict__ cosb, const float* __restrict__ sinb,
    const float* __restrict__ qw, const float* __restrict__ kw) {
  const int unit = blockIdx.x * 4 + (threadIdx.x >> 6);
  const int lane = threadIdx.x & 63;
  const int total_q = S_LEN * NH;
  float* base;
  const float* w;
  int pos;
  if (unit < total_q) {
    pos = unit >> 4;
    int head = unit & 15;
    base = qkv + (size_t)pos * QKV_W + head * DH;
    w = qw;
  } else {
    int u = unit - total_q;
    pos = u >> 2;
    int head = u & 3;
    base = qkv + (size_t)pos * QKV_W + 2048 + head * DH;
    w = kw;
  }
  float x0 = base[lane];
  float x1 = base[lane + 64];
  float ss = x0 * x0 + x1 * x1;
#pragma unroll
  for (int off = 32; off > 0; off >>= 1) ss += __shfl_xor(ss, off);
  float r = rsqrtf(ss * (1.0f / 128.0f) + EPS);
  float n0 = x0 * r * (1.0f + w[lane]);
  float n1 = x1 * r * (1.0f + w[lane + 64]);
  float c0 = cosb[(size_t)pos * DH + lane];
  float c1 = cosb[(size_t)pos * DH + lane + 64];
  float s0 = sinb[(size_t)pos * DH + lane];
  float s1 = sinb[(size_t)pos * DH + lane + 64];
  base[lane]      = n0 * c0 - n1 * s0;
  base[lane + 64] = n1 * c1 + n0 * s1;
}

// ---------------------------------------------------------------------------
// Pack K (cache ++ roped k) -> bf16 Kbf[4][4096][128], PRE-SWIZZLED within
// each 128-elem row: element d stored at d ^ ((key&7)<<3).  For current keys
// (>= CACHE_LEN) also emit the bf16 residual (lo = x - bf16(x)) to Klo
// [4][2048][128], same swizzle — used by vanilla_attn's split-precision QK.
// ---------------------------------------------------------------------------
__global__ __launch_bounds__(256) void pack_k(
    const float* __restrict__ qkv, const float* __restrict__ kcache,
    short* __restrict__ Kbf, short* __restrict__ Klo) {
  const int idx = blockIdx.x * 256 + threadIdx.x;
  const int e4 = idx * 4;
  const int kvh = e4 >> 19;
  const int rem = e4 & ((1 << 19) - 1);
  const int key = rem >> 7;
  const int d = rem & 127;
  const int dsw = d ^ ((key & 7) << 3);       // in-row XOR swizzle (8-elem units)
  if (key < CACHE_LEN) {
    float4 v = *(const float4*)(kcache + (((size_t)kvh * CACHE_LEN + key) << 7) + d);
    short4 o;
    o.x = f2bf(v.x); o.y = f2bf(v.y); o.z = f2bf(v.z); o.w = f2bf(v.w);
    *(short4*)(Kbf + (size_t)(e4 - d) + dsw) = o;
  } else {
    float4 v = *(const float4*)(qkv + (size_t)(key - CACHE_LEN) * QKV_W + 2048 + kvh * DH + d);
    short4 o;
    o.x = f2bf(v.x); o.y = f2bf(v.y); o.z = f2bf(v.z); o.w = f2bf(v.w);
    *(short4*)(Kbf + (size_t)(e4 - d) + dsw) = o;
    short4 ol;
    ol.x = f2bf(v.x - bf2f(o.x));
    ol.y = f2bf(v.y - bf2f(o.y));
    ol.z = f2bf(v.z - bf2f(o.z));
    ol.w = f2bf(v.w - bf2f(o.w));
    *(short4*)(Klo + ((size_t)kvh * 2048 + (key - CACHE_LEN)) * 128 + dsw) = ol;
  }
}

// ---------------------------------------------------------------------------
// Pack V transposed -> bf16 Vt[4][128][4096], PRE-SWIZZLED within each
// 64-key chunk: key c stored at c ^ ((d&7)<<3).
// ---------------------------------------------------------------------------
__global__ __launch_bounds__(256) void pack_vt(
    const float* __restrict__ qkv, const float* __restrict__ vcache,
    short* __restrict__ Vt) {
  __shared__ float tile[64][65];
  const int key0 = blockIdx.x * 64;
  const int d0 = blockIdx.y * 64;
  const int kvh = blockIdx.z;
  const int t = threadIdx.x;
  const int c = t & 63;
  const int r0 = t >> 6;
#pragma unroll
  for (int i = 0; i < 16; ++i) {
    int r = r0 + i * 4;
    int key = key0 + r;
    float v;
    if (key < CACHE_LEN)
      v = vcache[(((size_t)kvh * CACHE_LEN + key) << 7) + d0 + c];
    else
      v = qkv[(size_t)(key - CACHE_LEN) * QKV_W + 2560 + kvh * DH + d0 + c];
    tile[r][c] = v;
  }
  __syncthreads();
#pragma unroll
  for (int i = 0; i < 16; ++i) {
    int wr = r0 + i * 4;
    int csw = c ^ (((d0 + wr) & 7) << 3);     // in-chunk XOR swizzle
    Vt[((size_t)kvh * DH + d0 + wr) * 4096 + key0 + csw] = f2bf(tile[c][wr]);
  }
}

// ---------------------------------------------------------------------------
// Stage one 64-key K/V tile into an LDS buffer via global_load_lds (16B).
// 8 waves: per wave 2 GLDS for K (8 key-rows x 256B) + 2 GLDS for V
// (16 d-rows x 128B).  Global layouts are pre-swizzled, LDS dests linear.
// ---------------------------------------------------------------------------
static __device__ __forceinline__ void stage_kv(
    const short* Kb, const short* Vb, short* buf, int key0, int w, int lane) {
#pragma unroll
  for (int i = 0; i < 2; ++i)
    GLDS16(Kb + ((size_t)key0 + w * 8 + i * 4) * 128 + lane * 8,
           buf + (w * 8 + i * 4) * 128);
#pragma unroll
  for (int j = 0; j < 2; ++j)
    GLDS16(Vb + (size_t)(w * 16 + j * 8 + (lane >> 3)) * 4096 + key0 +
               (lane & 7) * 8,
           buf + 8192 + (w * 16 + j * 8) * 64);
}

// ---------------------------------------------------------------------------
// Lyra attention: 8 waves = 4 row-waves x 2 key-column-waves.
// Triple-buffered K/V staging via global_load_lds, one s_barrier per tile,
// counted s_waitcnt vmcnt(4).  Grid (hj=8, qt=32).
// ---------------------------------------------------------------------------
__global__ __launch_bounds__(512) void lyra_attn(
    const float* __restrict__ qkv,
    const short* __restrict__ Kbf,   // [4][4096][128] pre-swizzled rows
    const short* __restrict__ Vtb,   // [4][128][4096] pre-swizzled 64-chunks
    short* __restrict__ combined_bf) {
  __shared__ short sKV[3][16384];    // per buf: [0..8191]=K(key*128+e), [8192..]=Vt(d*64+e)
  __shared__ short sP[8][16][64];    // per-wave P tile, slot-XOR swizzled
  __shared__ float sL[64];
  const int hj = blockIdx.x;         // 0..7  (low bits -> XCD pin)
  const int qt = blockIdx.y;         // 0..31
  const int kvh = hj >> 1;
  const int t = threadIdx.x;
  const int w = t >> 6;              // 0..7
  const int lane = t & 63;
  const int quad = lane >> 4;
  const int l16 = lane & 15;
  const int wr = w >> 1;             // row-wave 0..3 (16 rows each)
  const int wc = w & 1;              // key-wave 0..1 (32 keys each)
  const int row0 = qt * 64;
  const int rbase = row0 + wr * 16 + quad * 4;
  const int swx = (l16 & 7) << 4;    // byte XOR for swizzled ds_read_b128

  // q fragments (fp32 global -> bf16 regs), rows wr*16+l16, full 128 dims
  bf16x8 qf[4];
  {
    const float* qrow =
        qkv + (size_t)(row0 + wr * 16 + l16) * QKV_W + (8 + hj) * DH;
#pragma unroll
    for (int ks = 0; ks < 4; ++ks) {
      float4 f0 = *(const float4*)(qrow + ks * 32 + quad * 8);
      float4 f1 = *(const float4*)(qrow + ks * 32 + quad * 8 + 4);
      qf[ks][0] = f2bf(f0.x); qf[ks][1] = f2bf(f0.y);
      qf[ks][2] = f2bf(f0.z); qf[ks][3] = f2bf(f0.w);
      qf[ks][4] = f2bf(f1.x); qf[ks][5] = f2bf(f1.y);
      qf[ks][6] = f2bf(f1.z); qf[ks][7] = f2bf(f1.w);
    }
  }
  bf16x8 onesf;
#pragma unroll
  for (int i = 0; i < 8; ++i) onesf[i] = (short)0x3F80;  // bf16 1.0

  f32x4 accO[8];
#pragma unroll
  for (int i = 0; i < 8; ++i) accO[i] = (f32x4){0.f, 0.f, 0.f, 0.f};
  f32x4 accL = (f32x4){0.f, 0.f, 0.f, 0.f};

  const short* Kb = Kbf + (size_t)kvh * 4096 * DH;
  const short* Vb = Vtb + (size_t)kvh * DH * 4096;

  // prologue: tiles 0,1 in flight (4 GLDS each per wave)
  stage_kv(Kb, Vb, &sKV[0][0], 0, w, lane);
  stage_kv(Kb, Vb, &sKV[1][0], 64, w, lane);

  short* sPw = &sP[w][0][0];
  int b = 0;
  for (int kt = 0; kt < 64; ++kt) {
    // my tile-kt loads done (4 newest = tile kt+1 still in flight), then sync
    asm volatile("s_waitcnt vmcnt(4)" ::: "memory");
    __builtin_amdgcn_s_barrier();
    __builtin_amdgcn_sched_barrier(0);

    // issue tile kt+2 into buffer (b+2)%3 (tile kt-1's buffer, fully read)
    {
      int nb = b + 2; if (nb >= 3) nb -= 3;
      stage_kv(Kb, Vb, &sKV[nb][0], ((kt + 2) & 63) * 64, w, lane);
    }

    const char* Ksc = (const char*)&sKV[b][0];
    const char* Vsc = (const char*)&sKV[b][8192];

    // QK^T: 16 rows (wr) x 32 keys (wc-slice)
    f32x4 accS[2];
#pragma unroll
    for (int s = 0; s < 2; ++s) accS[s] = (f32x4){0.f, 0.f, 0.f, 0.f};
    __builtin_amdgcn_s_setprio(1);
#pragma unroll
    for (int s = 0; s < 2; ++s) {
      const char* krow = Ksc + (wc * 32 + s * 16 + l16) * 256;
#pragma unroll
      for (int ks = 0; ks < 4; ++ks) {
        bf16x8 bk = *(const bf16x8*)(krow + ((ks * 64 + quad * 16) ^ swx));
        accS[s] = __builtin_amdgcn_mfma_f32_16x16x32_bf16(qf[ks], bk, accS[s],
                                                          0, 0, 0);
      }
    }
    __builtin_amdgcn_s_setprio(0);

    // fixed-max softmax: p = exp(s - 12); mask (+1.0) only for keys >= 2048.
    const int base = kt * 64 + wc * 32;
    if (kt >= 32) {
#pragma unroll
      for (int s = 0; s < 2; ++s) {
        const int col = base + s * 16 + l16;
#pragma unroll
        for (int r = 0; r < 4; ++r) {
          const int row = quad * 4 + r;
          float sc = accS[s][r] * SCALE;
          if ((col - CACHE_LEN) > (rbase + r)) sc += 1.0f;
          const int sl = (s * 2 + (l16 >> 3)) ^ (row & 7);
          sPw[row * 64 + sl * 8 + (l16 & 7)] = f2bf(__expf(sc - LYRA_C));
        }
      }
    } else {
#pragma unroll
      for (int s = 0; s < 2; ++s)
#pragma unroll
        for (int r = 0; r < 4; ++r) {
          const int row = quad * 4 + r;
          const int sl = (s * 2 + (l16 >> 3)) ^ (row & 7);
          sPw[row * 64 + sl * 8 + (l16 & 7)] =
              f2bf(__expf(accS[s][r] * SCALE - LYRA_C));
        }
    }

    // PV + row-sum over this wave's 32-key slice (K=32 -> one fragment)
    __builtin_amdgcn_s_setprio(1);
    bf16x8 ap = *(const bf16x8*)&sPw[l16 * 64 + ((quad ^ (l16 & 7)) << 3)];
    accL = __builtin_amdgcn_mfma_f32_16x16x32_bf16(ap, onesf, accL, 0, 0, 0);
#pragma unroll
    for (int t8 = 0; t8 < 8; ++t8) {
      bf16x8 bv = *(const bf16x8*)(
          Vsc + (t8 * 16 + l16) * 128 + ((wc * 64 + quad * 16) ^ swx));
      accO[t8] = __builtin_amdgcn_mfma_f32_16x16x32_bf16(ap, bv, accO[t8],
                                                         0, 0, 0);
    }
    __builtin_amdgcn_s_setprio(0);

    ++b; if (b == 3) b = 0;
  }

  // epilogue: merge wc partials through LDS (buffer 0 fully read; in-flight
  // GLDS target bufs 1,2), normalize, write bf16 output.
  __syncthreads();
  float* sO = (float*)&sKV[0][0];    // [64 rows][128] f32 = 32 KB
  if (wc == 1) {
#pragma unroll
    for (int t8 = 0; t8 < 8; ++t8)
#pragma unroll
      for (int r = 0; r < 4; ++r)
        sO[((wr * 16 + quad * 4 + r) << 7) + t8 * 16 + l16] = accO[t8][r];
    if (l16 == 0) {
#pragma unroll
      for (int r = 0; r < 4; ++r) sL[wr * 16 + quad * 4 + r] = accL[r];
    }
  }
  __syncthreads();
  if (wc == 0) {
    float linv[4];
#pragma unroll
    for (int r = 0; r < 4; ++r)
      linv[r] = 1.0f / (accL[r] + sL[wr * 16 + quad * 4 + r]);
#pragma unroll
    for (int t8 = 0; t8 < 8; ++t8)
#pragma unroll
      for (int r = 0; r < 4; ++r) {
        float o = accO[t8][r] + sO[((wr * 16 + quad * 4 + r) << 7) + t8 * 16 + l16];
        combined_bf[(size_t)(rbase + r) * HID + (8 + hj) * DH + t8 * 16 + l16] =
            f2bf(o * linv[r]);
      }
  }
}

// ---------------------------------------------------------------------------
// Stage one 64-key Khi/Klo/V tile (vanilla path) via global_load_lds.
// Per wave 6 GLDS.  buf layout: [0..8191]=Khi, [8192..16383]=Klo,
// [16384..24575]=Vt.
// ---------------------------------------------------------------------------
static __device__ __forceinline__ void stage_van(
    const short* Kh, const short* Kl, const short* Vb, short* buf,
    int key0, int w, int lane) {
#pragma unroll
  for (int i = 0; i < 2; ++i) {
    GLDS16(Kh + ((size_t)key0 + w * 8 + i * 4) * 128 + lane * 8,
           buf + (w * 8 + i * 4) * 128);
    GLDS16(Kl + ((size_t)key0 + w * 8 + i * 4) * 128 + lane * 8,
           buf + 8192 + (w * 8 + i * 4) * 128);
  }
#pragma unroll
  for (int j = 0; j < 2; ++j)
    GLDS16(Vb + (size_t)(w * 16 + j * 8 + (lane >> 3)) * 4096 + key0 +
               (lane & 7) * 8,
           buf + 16384 + (w * 16 + j * 8) * 64);
}

// ---------------------------------------------------------------------------
// Fused vanilla attention (flash-style, fixed-shift softmax).
// Grid (h=8, qt=32), 512 threads = 4 row-waves x 2 key-waves, causal
// kt = 0..qt.  Per tile: split-precision QK (q=qh+ql, k=kh+kl; 3 MFMA ->
// score err ~1e-5), p = exp(s*SCALE-12) fp32 -> written UNNORMALIZED to
// wout; exact fp32 row-sums via shfl; PV accumulates bf16 p into accO.
// Epilogue: merge wc partials, write normalized O (combined heads 0..7)
// and 1/rowsum to vinv.  vnorm then scales wout rows + zero-fills j>row.
// exp(s-12)/sum == softmax exactly (shift cancels); p <= e^7 fp32-safe.
// Double-buffered staging, vmcnt(0)+barrier per tile (loads for tile kt+1
// issued right after the barrier overlap the whole tile-kt compute).
// ---------------------------------------------------------------------------
__global__ __launch_bounds__(512) void vanilla_attn(
    const float* __restrict__ qkv,
    const short* __restrict__ Kbf,   // hi keys: rows 2048.. of Kbf
    const short* __restrict__ Klo,   // [4][2048][128] residuals, same swizzle
    const short* __restrict__ Vtb,   // cols 2048.. are current v
    float* __restrict__ wout,
    float* __restrict__ vinv,        // [8][2048] 1/rowsum
    short* __restrict__ combined_bf) {
  __shared__ short sKV[2][24576];    // Khi | Klo | Vt  (48 KB each buf)
  __shared__ short sP[8][16][64];    // per-wave P tile, slot-XOR swizzled
  __shared__ float sL[64];
  const int hj = blockIdx.x;         // head 0..7
  const int qt = blockIdx.y;         // 0..31
  const int kvh = hj >> 1;
  const int t = threadIdx.x;
  const int w = t >> 6;
  const int lane = t & 63;
  const int quad = lane >> 4;
  const int l16 = lane & 15;
  const int wr = w >> 1;
  const int wc = w & 1;
  const int row0 = qt * 64;
  const int rbase = row0 + wr * 16 + quad * 4;
  const int swx = (l16 & 7) << 4;

  // q hi/lo fragments from fp32
  bf16x8 qh[4], ql[4];
  {
    const float* qrow =
        qkv + (size_t)(row0 + wr * 16 + l16) * QKV_W + hj * DH;
#pragma unroll
    for (int ks = 0; ks < 4; ++ks) {
#pragma unroll
      for (int e = 0; e < 8; ++e) {
        float x = qrow[ks * 32 + quad * 8 + e];
        short h = f2bf(x);
        qh[ks][e] = h;
        ql[ks][e] = f2bf(x - bf2f(h));
      }
    }
  }

  f32x4 accO[8];
#pragma unroll
  for (int i = 0; i < 8; ++i) accO[i] = (f32x4){0.f, 0.f, 0.f, 0.f};
  float accR[4] = {0.f, 0.f, 0.f, 0.f};

  const short* Kh = Kbf + ((size_t)kvh * 4096 + 2048) * DH;
  const short* Kl = Klo + (size_t)kvh * 2048 * DH;
  const short* Vb = Vtb + (size_t)kvh * DH * 4096 + 2048;  // current-v cols
  float* wrow = wout + (size_t)hj * S_LEN * S_LEN;

  stage_van(Kh, Kl, Vb, &sKV[0][0], 0, w, lane);

  short* sPw = &sP[w][0][0];
  int b = 0;
  for (int kt = 0; kt <= qt; ++kt) {
    asm volatile("s_waitcnt vmcnt(0)" ::: "memory");
    __builtin_amdgcn_s_barrier();
    __builtin_amdgcn_sched_barrier(0);

    // stage tile kt+1 into the other buffer (its readers finished kt-1,
    // guaranteed by the barrier above); overlaps all of tile-kt compute.
    if (kt < qt)
      stage_van(Kh, Kl, Vb, &sKV[b ^ 1][0], (kt + 1) * 64, w, lane);

    const char* Khs = (const char*)&sKV[b][0];
    const char* Kls = (const char*)&sKV[b][8192];
    const char* Vsc = (const char*)&sKV[b][16384];

    // split-precision QK^T: 16 rows x 32 keys per wave
    f32x4 accS[2];
#pragma unroll
    for (int s = 0; s < 2; ++s) accS[s] = (f32x4){0.f, 0.f, 0.f, 0.f};
    __builtin_amdgcn_s_setprio(1);
#pragma unroll
    for (int s = 0; s < 2; ++s) {
      const char* krh = Khs + (wc * 32 + s * 16 + l16) * 256;
      const char* krl = Kls + (wc * 32 + s * 16 + l16) * 256;
#pragma unroll
      for (int ks = 0; ks < 4; ++ks) {
        const int off = (ks * 64 + quad * 16) ^ swx;
        bf16x8 kh = *(const bf16x8*)(krh + off);
        bf16x8 kl = *(const bf16x8*)(krl + off);
        accS[s] = __builtin_amdgcn_mfma_f32_16x16x32_bf16(qh[ks], kh, accS[s], 0, 0, 0);
        accS[s] = __builtin_amdgcn_mfma_f32_16x16x32_bf16(ql[ks], kh, accS[s], 0, 0, 0);
        accS[s] = __builtin_amdgcn_mfma_f32_16x16x32_bf16(qh[ks], kl, accS[s], 0, 0, 0);
      }
    }
    __builtin_amdgcn_s_setprio(0);

    // p = exp(s*SCALE - 12); causal zero on diagonal tile; write raw p to w
    const int key0 = kt * 64;
    const bool diag = (kt == qt);
    float pr[4] = {0.f, 0.f, 0.f, 0.f};
#pragma unroll
    for (int s = 0; s < 2; ++s) {
      const int col = key0 + wc * 32 + s * 16 + l16;
#pragma unroll
      for (int r = 0; r < 4; ++r) {
        const int row = quad * 4 + r;
        const int grow = rbase + r;
        float p = __expf(accS[s][r] * SCALE - LYRA_C);
        if (diag && col > grow) p = 0.f;
        pr[r] += p;
        const int sl = (s * 2 + (l16 >> 3)) ^ (row & 7);
        sPw[row * 64 + sl * 8 + (l16 & 7)] = f2bf(p);
        wrow[(size_t)grow * S_LEN + col] = p;
      }
    }
    // exact fp32 row-sum across the 16 key-lanes of this wave's slice
#pragma unroll
    for (int r = 0; r < 4; ++r) {
      float v = pr[r];
      v += __shfl_xor(v, 1);
      v += __shfl_xor(v, 2);
      v += __shfl_xor(v, 4);
      v += __shfl_xor(v, 8);
      accR[r] += v;
    }

    // PV over this wave's 32-key slice
    __builtin_amdgcn_s_setprio(1);
    bf16x8 ap = *(const bf16x8*)&sPw[l16 * 64 + ((quad ^ (l16 & 7)) << 3)];
#pragma unroll
    for (int t8 = 0; t8 < 8; ++t8) {
      bf16x8 bv = *(const bf16x8*)(
          Vsc + (t8 * 16 + l16) * 128 + ((wc * 64 + quad * 16) ^ swx));
      accO[t8] = __builtin_amdgcn_mfma_f32_16x16x32_bf16(ap, bv, accO[t8],
                                                         0, 0, 0);
    }
    __builtin_amdgcn_s_setprio(0);

    b ^= 1;
  }

  // epilogue: merge wc partials; write normalized O and 1/rowsum.
  __syncthreads();
  float* sO = (float*)&sKV[0][0];    // 32 KB scratch (no in-flight GLDS)
  if (wc == 1) {
#pragma unroll
    for (int t8 = 0; t8 < 8; ++t8)
#pragma unroll
      for (int r = 0; r < 4; ++r)
        sO[((wr * 16 + quad * 4 + r) << 7) + t8 * 16 + l16] = accO[t8][r];
    if (l16 == 0) {
#pragma unroll
      for (int r = 0; r < 4; ++r) sL[wr * 16 + quad * 4 + r] = accR[r];
    }
  }
  __syncthreads();
  if (wc == 0) {
    float linv[4];
#pragma unroll
    for (int r = 0; r < 4; ++r)
      linv[r] = 1.0f / (accR[r] + sL[wr * 16 + quad * 4 + r]);
    if (l16 == 0) {
#pragma unroll
      for (int r = 0; r < 4; ++r) vinv[hj * S_LEN + rbase + r] = linv[r];
    }
#pragma unroll
    for (int t8 = 0; t8 < 8; ++t8)
#pragma unroll
      for (int r = 0; r < 4; ++r) {
        float o = accO[t8][r] + sO[((wr * 16 + quad * 4 + r) << 7) + t8 * 16 + l16];
        combined_bf[(size_t)(rbase + r) * HID + hj * DH + t8 * 16 + l16] =
            f2bf(o * linv[r]);
      }
  }
}

// ---------------------------------------------------------------------------
// Normalize vanilla_w rows by stored 1/rowsum; zero-fill j > row.
// ---------------------------------------------------------------------------
__global__ __launch_bounds__(256) void vnorm(
    const float* __restrict__ vinv, float* __restrict__ wout) {
  const int row = blockIdx.x;
  const int h = blockIdx.y;
  float* p = wout + (size_t)h * S_LEN * S_LEN + (size_t)row * S_LEN;
  const float inv = vinv[h * S_LEN + row];
  const int t = threadIdx.x;
#pragma unroll
  for (int i = 0; i < 2; ++i) {
    const int j = (t + i * 256) * 4;
    float4 v;
    if (j > row) {
      v = make_float4(0.f, 0.f, 0.f, 0.f);
    } else if (j + 3 <= row) {
      v = *(const float4*)(p + j);
      v.x *= inv; v.y *= inv; v.z *= inv; v.w *= inv;
    } else {
      v = *(const float4*)(p + j);
      v.x = (j + 0 <= row) ? v.x * inv : 0.f;
      v.y = (j + 1 <= row) ? v.y * inv : 0.f;
      v.z = (j + 2 <= row) ? v.z * inv : 0.f;
      v.w = (j + 3 <= row) ? v.w * inv : 0.f;
    }
    *(float4*)(p + j) = v;
  }
}

// ---------------------------------------------------------------------------
extern "C" void kernel_launch(void* const* d_in, const int* in_sizes, int n_in,
                              void* d_out, int out_size, void* d_ws, size_t ws_size,
                              hipStream_t stream) {
  (void)in_sizes; (void)n_in; (void)out_size; (void)ws_size;
  const float* hidden = (const float*)d_in[0];
  const float* cosb   = (const float*)d_in[1];
  const float* sinb   = (const float*)d_in[2];
  const float* kcache = (const float*)d_in[4];
  const float* vcache = (const float*)d_in[5];
  const float* Wq = (const float*)d_in[6];
  const float* Wk = (const float*)d_in[7];
  const float* Wv = (const float*)d_in[8];
  const float* Wo = (const float*)d_in[9];
  const float* qw = (const float*)d_in[10];
  const float* kw = (const float*)d_in[11];

  float* out  = (float*)d_out;                     // attn_output [2048*2048]
  float* wout = out + (size_t)4194304;             // vanilla_w   [8*2048*2048]

  // d_ws: qkv f32 | Kbf | Vtb | combined_bf | Wo_bf
  float* qkv = (float*)d_ws;                       // [2048 x 3072] f32
  short* Kbf = (short*)(qkv + (size_t)2048 * QKV_W);
  short* Vtb = Kbf + (size_t)4 * 4096 * DH;
  short* combined_bf = Vtb + (size_t)4 * DH * 4096;   // [2048 x 2048] bf16
  short* Wo_bf = combined_bf + (size_t)2048 * HID;    // [2048 x 2048] bf16

  // transient scratch inside wout (consumed by gemm qkv before vanilla_attn
  // overwrites wout):
  short* hidden_bf = (short*)wout;                    // [2048 x 2048] bf16
  short* Wqkv_bf = hidden_bf + (size_t)2048 * HID;    // [3072 x 2048] bf16

  // transient scratch inside attn_output (dead before final gemm writes it):
  short* Klo  = (short*)out;                          // [4][2048][128] bf16 = 2 MB
  float* vinv = (float*)(Klo + (size_t)4 * 2048 * DH); // [8][2048] f32 = 64 KB

  pack_bf16<<<dim3(2048), 256, 0, stream>>>(hidden, hidden_bf);
  pack_bf16<<<dim3(2048), 256, 0, stream>>>(Wq, Wqkv_bf);
  pack_bf16<<<dim3(512), 256, 0, stream>>>(Wk, Wqkv_bf + (size_t)2048 * 2048);
  pack_bf16<<<dim3(512), 256, 0, stream>>>(Wv, Wqkv_bf + (size_t)2560 * 2048);
  pack_bf16<<<dim3(2048), 256, 0, stream>>>(Wo, Wo_bf);

  gemm_bf16<<<dim3(24, 16), 256, 0, stream>>>(hidden_bf, Wqkv_bf, qkv, 2048, QKV_W);
  rms_rope<<<dim3(10240), 256, 0, stream>>>(qkv, cosb, sinb, qw, kw);
  pack_k<<<dim3(2048), 256, 0, stream>>>(qkv, kcache, Kbf, Klo);
  pack_vt<<<dim3(64, 2, 4), 256, 0, stream>>>(qkv, vcache, Vtb);
  lyra_attn<<<dim3(8, 32), 512, 0, stream>>>(qkv, Kbf, Vtb, combined_bf);
  vanilla_attn<<<dim3(8, 32), 512, 0, stream>>>(qkv, Kbf, Klo, Vtb, wout, vinv,
                                                combined_bf);
  vnorm<<<dim3(2048, 8), 256, 0, stream>>>(vinv, wout);
  gemm_bf16<<<dim3(16, 16), 256, 0, stream>>>(combined_bf, Wo_bf, out, 2048, HID);
}

// Round 4
// 496.259 us; speedup vs baseline: 1.3783x; 1.0338x over previous
//
#include <hip/hip_runtime.h>
#include <math.h>

#define S_LEN 2048
#define HID 2048
#define NH 16
#define NKV 4
#define DH 128
#define CACHE_LEN 2048
#define QKV_W 3072   // q(2048) | k(512) | v(512) packed per row
#define SCALE 0.08838834764831845f
#define EPS 1e-6f
#define LYRA_C 12.0f // fixed softmax max-bound: |scores| <= ~19, exp(s-12) safe

typedef short bf16x8 __attribute__((ext_vector_type(8)));
typedef float f32x4 __attribute__((ext_vector_type(4)));

static __device__ __forceinline__ short f2bf(float x) {
  union { float f; unsigned u; } v; v.f = x;
  unsigned r = (v.u + 0x7FFF + ((v.u >> 16) & 1)) >> 16;
  return (short)r;
}

static __device__ __forceinline__ float bf2f(short h) {
  union { unsigned u; float f; } v;
  v.u = ((unsigned)(unsigned short)h) << 16;
  return v.f;
}

#define GLDS16(g, l)                                                      \
  __builtin_amdgcn_global_load_lds(                                       \
      (const __attribute__((address_space(1))) unsigned int*)(g),         \
      (__attribute__((address_space(3))) unsigned int*)(l), 16, 0, 0)

// ---------------------------------------------------------------------------
// fp32 -> bf16 pack, 8 elements/thread.
// ---------------------------------------------------------------------------
__global__ __launch_bounds__(256) void pack_bf16(
    const float* __restrict__ src, short* __restrict__ dst) {
  const int i = (blockIdx.x * 256 + threadIdx.x) * 8;
  float4 a = *(const float4*)(src + i);
  float4 b = *(const float4*)(src + i + 4);
  bf16x8 o;
  o[0] = f2bf(a.x); o[1] = f2bf(a.y); o[2] = f2bf(a.z); o[3] = f2bf(a.w);
  o[4] = f2bf(b.x); o[5] = f2bf(b.y); o[6] = f2bf(b.z); o[7] = f2bf(b.w);
  *(bf16x8*)(dst + i) = o;
}

// ---------------------------------------------------------------------------
// bf16 MFMA GEMM: C[M x N] fp32 = A[M x K]bf16 * B[N x K]bf16^T.
// ---------------------------------------------------------------------------
__global__ __launch_bounds__(256) void gemm_bf16(
    const short* __restrict__ A, const short* __restrict__ B,
    float* __restrict__ C, int K, int ldc) {
  __shared__ short sA[4096];
  __shared__ short sB[4096];
  const int t = threadIdx.x;
  const int w = t >> 6;
  const int lane = t & 63;
  const int quad = lane >> 4;
  const int l16 = lane & 15;
  const int tm = blockIdx.y * 128;
  const int tn = blockIdx.x * 128;
  const int srow = lane >> 2;
  const int scol = (lane & 3) * 8;
  const int mblk = (w & 1) * 64;
  const int nblk = (w >> 1) * 64;
  f32x4 acc[4][4];
#pragma unroll
  for (int i = 0; i < 4; ++i)
#pragma unroll
    for (int j = 0; j < 4; ++j) acc[i][j] = (f32x4){0.f, 0.f, 0.f, 0.f};

  const short* Ab = A + (size_t)(tm + w * 32 + srow) * K + scol;
  const short* Bb = B + (size_t)(tn + w * 32 + srow) * K + scol;
  const size_t rstep = (size_t)16 * K;

  for (int k0 = 0; k0 < K; k0 += 32) {
    GLDS16(Ab + k0, sA + (w * 2 + 0) * 512);
    GLDS16(Ab + rstep + k0, sA + (w * 2 + 1) * 512);
    GLDS16(Bb + k0, sB + (w * 2 + 0) * 512);
    GLDS16(Bb + rstep + k0, sB + (w * 2 + 1) * 512);
    __syncthreads();
    bf16x8 af[4], bfv[4];
#pragma unroll
    for (int ms = 0; ms < 4; ++ms)
      af[ms] = *(const bf16x8*)&sA[(mblk + ms * 16 + l16) * 32 + quad * 8];
#pragma unroll
    for (int ns = 0; ns < 4; ++ns)
      bfv[ns] = *(const bf16x8*)&sB[(nblk + ns * 16 + l16) * 32 + quad * 8];
#pragma unroll
    for (int ms = 0; ms < 4; ++ms)
#pragma unroll
      for (int ns = 0; ns < 4; ++ns)
        acc[ms][ns] = __builtin_amdgcn_mfma_f32_16x16x32_bf16(
            af[ms], bfv[ns], acc[ms][ns], 0, 0, 0);
    __syncthreads();
  }
#pragma unroll
  for (int ms = 0; ms < 4; ++ms)
#pragma unroll
    for (int ns = 0; ns < 4; ++ns) {
      const int row = tm + mblk + ms * 16 + quad * 4;
      const int col = tn + nblk + ns * 16 + l16;
#pragma unroll
      for (int r = 0; r < 4; ++r)
        C[(size_t)(row + r) * ldc + col] = acc[ms][ns][r];
    }
}

// ---------------------------------------------------------------------------
// RMSNorm(+1+w) then RoPE, in-place on q (16 heads) and k (4 heads).
// ---------------------------------------------------------------------------
__global__ __launch_bounds__(256) void rms_rope(
    float* __restrict__ qkv,
    const float* __restrict__ cosb, const float* __restrict__ sinb,
    const float* __restrict__ qw, const float* __restrict__ kw) {
  const int unit = blockIdx.x * 4 + (threadIdx.x >> 6);
  const int lane = threadIdx.x & 63;
  const int total_q = S_LEN * NH;
  float* base;
  const float* w;
  int pos;
  if (unit < total_q) {
    pos = unit >> 4;
    int head = unit & 15;
    base = qkv + (size_t)pos * QKV_W + head * DH;
    w = qw;
  } else {
    int u = unit - total_q;
    pos = u >> 2;
    int head = u & 3;
    base = qkv + (size_t)pos * QKV_W + 2048 + head * DH;
    w = kw;
  }
  float x0 = base[lane];
  float x1 = base[lane + 64];
  float ss = x0 * x0 + x1 * x1;
#pragma unroll
  for (int off = 32; off > 0; off >>= 1) ss += __shfl_xor(ss, off);
  float r = rsqrtf(ss * (1.0f / 128.0f) + EPS);
  float n0 = x0 * r * (1.0f + w[lane]);
  float n1 = x1 * r * (1.0f + w[lane + 64]);
  float c0 = cosb[(size_t)pos * DH + lane];
  float c1 = cosb[(size_t)pos * DH + lane + 64];
  float s0 = sinb[(size_t)pos * DH + lane];
  float s1 = sinb[(size_t)pos * DH + lane + 64];
  base[lane]      = n0 * c0 - n1 * s0;
  base[lane + 64] = n1 * c1 + n0 * s1;
}

// ---------------------------------------------------------------------------
// Pack K (cache ++ roped k) -> bf16 Kbf[4][4096][128], PRE-SWIZZLED within
// each 128-elem row: element d stored at d ^ ((key&7)<<3).  For current keys
// (>= CACHE_LEN) also emit the bf16 residual (lo = x - bf16(x)) to Klo
// [4][2048][128], same swizzle — used by vanilla_attn's split-precision QK.
// ---------------------------------------------------------------------------
__global__ __launch_bounds__(256) void pack_k(
    const float* __restrict__ qkv, const float* __restrict__ kcache,
    short* __restrict__ Kbf, short* __restrict__ Klo) {
  const int idx = blockIdx.x * 256 + threadIdx.x;
  const int e4 = idx * 4;
  const int kvh = e4 >> 19;
  const int rem = e4 & ((1 << 19) - 1);
  const int key = rem >> 7;
  const int d = rem & 127;
  const int dsw = d ^ ((key & 7) << 3);       // in-row XOR swizzle (8-elem units)
  if (key < CACHE_LEN) {
    float4 v = *(const float4*)(kcache + (((size_t)kvh * CACHE_LEN + key) << 7) + d);
    short4 o;
    o.x = f2bf(v.x); o.y = f2bf(v.y); o.z = f2bf(v.z); o.w = f2bf(v.w);
    *(short4*)(Kbf + (size_t)(e4 - d) + dsw) = o;
  } else {
    float4 v = *(const float4*)(qkv + (size_t)(key - CACHE_LEN) * QKV_W + 2048 + kvh * DH + d);
    short4 o;
    o.x = f2bf(v.x); o.y = f2bf(v.y); o.z = f2bf(v.z); o.w = f2bf(v.w);
    *(short4*)(Kbf + (size_t)(e4 - d) + dsw) = o;
    short4 ol;
    ol.x = f2bf(v.x - bf2f(o.x));
    ol.y = f2bf(v.y - bf2f(o.y));
    ol.z = f2bf(v.z - bf2f(o.z));
    ol.w = f2bf(v.w - bf2f(o.w));
    *(short4*)(Klo + ((size_t)kvh * 2048 + (key - CACHE_LEN)) * 128 + dsw) = ol;
  }
}

// ---------------------------------------------------------------------------
// Pack V transposed -> bf16 Vt[4][128][4096], PRE-SWIZZLED within each
// 64-key chunk: key c stored at c ^ ((d&7)<<3).
// ---------------------------------------------------------------------------
__global__ __launch_bounds__(256) void pack_vt(
    const float* __restrict__ qkv, const float* __restrict__ vcache,
    short* __restrict__ Vt) {
  __shared__ float tile[64][65];
  const int key0 = blockIdx.x * 64;
  const int d0 = blockIdx.y * 64;
  const int kvh = blockIdx.z;
  const int t = threadIdx.x;
  const int c = t & 63;
  const int r0 = t >> 6;
#pragma unroll
  for (int i = 0; i < 16; ++i) {
    int r = r0 + i * 4;
    int key = key0 + r;
    float v;
    if (key < CACHE_LEN)
      v = vcache[(((size_t)kvh * CACHE_LEN + key) << 7) + d0 + c];
    else
      v = qkv[(size_t)(key - CACHE_LEN) * QKV_W + 2560 + kvh * DH + d0 + c];
    tile[r][c] = v;
  }
  __syncthreads();
#pragma unroll
  for (int i = 0; i < 16; ++i) {
    int wr = r0 + i * 4;
    int csw = c ^ (((d0 + wr) & 7) << 3);     // in-chunk XOR swizzle
    Vt[((size_t)kvh * DH + d0 + wr) * 4096 + key0 + csw] = f2bf(tile[c][wr]);
  }
}

// ---------------------------------------------------------------------------
// Stage one 128-key K/V tile into an LDS buffer via global_load_lds (16B).
// Per wave: 4 GLDS for K (16 key-rows x 256B) + 4 GLDS for V (16 d-rows x
// 256B).  Global layouts are pre-swizzled, LDS dests linear (rule 21).
// buf layout (shorts): [0..16383]=K(key*128+e), [16384..32767]=Vt(d*128+key)
// ---------------------------------------------------------------------------
static __device__ __forceinline__ void stage_kv128(
    const short* Kb, const short* Vb, short* buf, int key0, int w, int lane) {
#pragma unroll
  for (int i = 0; i < 4; ++i)
    GLDS16(Kb + ((size_t)key0 + w * 16 + i * 4) * 128 + lane * 8,
           buf + (w * 16 + i * 4) * 128);
#pragma unroll
  for (int i = 0; i < 4; ++i)
    GLDS16(Vb + (size_t)(w * 16 + i * 4 + (lane >> 4)) * 4096 + key0 +
               (lane & 15) * 8,
           buf + 16384 + (w * 16 + i * 4) * 128);
}

// ---------------------------------------------------------------------------
// Lyra attention: 8 waves = 2 row-waves (32 rows = 2 MFMA groups) x 4
// key-waves (32 keys of a 128-key tile).  Each K/V LDS read feeds 2 MFMAs
// (2x register reuse vs 16-row waves).  Double-buffered 64KB K/V staging,
// one barrier per 128-key tile.  sP per-wave [2 groups][16][64] with the
// proven slot^(row&7) XOR.  Epilogue merges 4 wc-partials through the dead
// K/V buffers.  Grid (hj=8, qt=32): id%8==hj pins each kvh to one XCD L2.
// ---------------------------------------------------------------------------
__global__ __launch_bounds__(512) void lyra_attn(
    const float* __restrict__ qkv,
    const short* __restrict__ Kbf,   // [4][4096][128] pre-swizzled rows
    const short* __restrict__ Vtb,   // [4][128][4096] pre-swizzled 64-chunks
    short* __restrict__ combined_bf) {
  __shared__ short sKV[2][32768];    // 2 x (K 32KB | Vt 32KB)
  __shared__ short sP[8][2][1024];   // per-wave, per-group [16][64]
  const int hj = blockIdx.x;
  const int qt = blockIdx.y;
  const int kvh = hj >> 1;
  const int t = threadIdx.x;
  const int w = t >> 6;
  const int lane = t & 63;
  const int quad = lane >> 4;
  const int l16 = lane & 15;
  const int wr = w >> 2;             // 0..1 : 32 rows
  const int wc = w & 3;              // 0..3 : 32-key slice of 128
  const int row0 = qt * 64;
  const int swx = (l16 & 7) << 4;    // byte XOR for swizzled ds_read_b128
  // V byte offset within a 256B d-row for this wave's 32 keys:
  const int voff = (wc >> 1) * 128 + ((((wc & 1) * 64) + quad * 16) ^ swx);

  // q fragments: 2 row-groups x 4 k-slices
  bf16x8 qf[2][4];
#pragma unroll
  for (int g = 0; g < 2; ++g) {
    const float* qrow =
        qkv + (size_t)(row0 + wr * 32 + g * 16 + l16) * QKV_W + (8 + hj) * DH;
#pragma unroll
    for (int ks = 0; ks < 4; ++ks) {
      float4 f0 = *(const float4*)(qrow + ks * 32 + quad * 8);
      float4 f1 = *(const float4*)(qrow + ks * 32 + quad * 8 + 4);
      qf[g][ks][0] = f2bf(f0.x); qf[g][ks][1] = f2bf(f0.y);
      qf[g][ks][2] = f2bf(f0.z); qf[g][ks][3] = f2bf(f0.w);
      qf[g][ks][4] = f2bf(f1.x); qf[g][ks][5] = f2bf(f1.y);
      qf[g][ks][6] = f2bf(f1.z); qf[g][ks][7] = f2bf(f1.w);
    }
  }
  bf16x8 onesf;
#pragma unroll
  for (int i = 0; i < 8; ++i) onesf[i] = (short)0x3F80;  // bf16 1.0

  f32x4 accO[2][8];
#pragma unroll
  for (int g = 0; g < 2; ++g)
#pragma unroll
    for (int i = 0; i < 8; ++i) accO[g][i] = (f32x4){0.f, 0.f, 0.f, 0.f};
  f32x4 accL[2];
  accL[0] = (f32x4){0.f, 0.f, 0.f, 0.f};
  accL[1] = (f32x4){0.f, 0.f, 0.f, 0.f};

  const short* Kb = Kbf + (size_t)kvh * 4096 * DH;
  const short* Vb = Vtb + (size_t)kvh * DH * 4096;

  stage_kv128(Kb, Vb, &sKV[0][0], 0, w, lane);

  int b = 0;
  for (int kt = 0; kt < 32; ++kt) {
    asm volatile("s_waitcnt vmcnt(0)" ::: "memory");
    __builtin_amdgcn_s_barrier();
    __builtin_amdgcn_sched_barrier(0);

    if (kt < 31)
      stage_kv128(Kb, Vb, &sKV[b ^ 1][0], (kt + 1) * 128, w, lane);

    const char* Ksc = (const char*)&sKV[b][0];
    const char* Vsc = (const char*)&sKV[b][16384];

    // QK^T: 32 rows x 32 keys; each bk read feeds both row-groups.
    f32x4 accS[2][2];
#pragma unroll
    for (int g = 0; g < 2; ++g)
#pragma unroll
      for (int s = 0; s < 2; ++s) accS[g][s] = (f32x4){0.f, 0.f, 0.f, 0.f};
    __builtin_amdgcn_s_setprio(1);
#pragma unroll
    for (int s = 0; s < 2; ++s) {
      const char* krow = Ksc + (wc * 32 + s * 16 + l16) * 256;
#pragma unroll
      for (int ks = 0; ks < 4; ++ks) {
        bf16x8 bk = *(const bf16x8*)(krow + ((ks * 64 + quad * 16) ^ swx));
        accS[0][s] = __builtin_amdgcn_mfma_f32_16x16x32_bf16(qf[0][ks], bk, accS[0][s], 0, 0, 0);
        accS[1][s] = __builtin_amdgcn_mfma_f32_16x16x32_bf16(qf[1][ks], bk, accS[1][s], 0, 0, 0);
      }
    }
    __builtin_amdgcn_s_setprio(0);

    // fixed-max softmax: p = exp(s*SCALE - 12); mask (+1.0) iff
    // col - CACHE_LEN > row (false automatically for cached keys).
    const int base = kt * 128 + wc * 32;
#pragma unroll
    for (int g = 0; g < 2; ++g) {
      short* sPg = &sP[w][g][0];
#pragma unroll
      for (int s = 0; s < 2; ++s) {
        const int col = base + s * 16 + l16;
#pragma unroll
        for (int r = 0; r < 4; ++r) {
          const int row = quad * 4 + r;
          const int grow = row0 + wr * 32 + g * 16 + row;
          float sc = accS[g][s][r] * SCALE;
          if ((col - CACHE_LEN) > grow) sc += 1.0f;
          const int sl = (s * 2 + (l16 >> 3)) ^ (row & 7);
          sPg[row * 64 + sl * 8 + (l16 & 7)] = f2bf(__expf(sc - LYRA_C));
        }
      }
    }

    // PV + row-sum; each bv read feeds both row-groups.
    __builtin_amdgcn_s_setprio(1);
    bf16x8 ap0 = *(const bf16x8*)&sP[w][0][l16 * 64 + ((quad ^ (l16 & 7)) << 3)];
    bf16x8 ap1 = *(const bf16x8*)&sP[w][1][l16 * 64 + ((quad ^ (l16 & 7)) << 3)];
    accL[0] = __builtin_amdgcn_mfma_f32_16x16x32_bf16(ap0, onesf, accL[0], 0, 0, 0);
    accL[1] = __builtin_amdgcn_mfma_f32_16x16x32_bf16(ap1, onesf, accL[1], 0, 0, 0);
#pragma unroll
    for (int t8 = 0; t8 < 8; ++t8) {
      bf16x8 bv = *(const bf16x8*)(Vsc + (t8 * 16 + l16) * 256 + voff);
      accO[0][t8] = __builtin_amdgcn_mfma_f32_16x16x32_bf16(ap0, bv, accO[0][t8], 0, 0, 0);
      accO[1][t8] = __builtin_amdgcn_mfma_f32_16x16x32_bf16(ap1, bv, accO[1][t8], 0, 0, 0);
    }
    __builtin_amdgcn_s_setprio(0);

    b ^= 1;
  }

  // epilogue: merge 4 wc-partials (wc 1..3 via 96KB of dead sKV + sL in sP),
  // normalize, write bf16 output.
  __syncthreads();
  float* sO = (float*)&sKV[0][0];
  float* sLa = (float*)&sP[0][0][0];  // [3][64]
  if (wc != 0) {
    float* dst = sO + (size_t)(wc - 1) * 8192;
#pragma unroll
    for (int g = 0; g < 2; ++g)
#pragma unroll
      for (int t8 = 0; t8 < 8; ++t8)
#pragma unroll
        for (int r = 0; r < 4; ++r) {
          const int rl = wr * 32 + g * 16 + quad * 4 + r;
          dst[rl * 128 + t8 * 16 + l16] = accO[g][t8][r];
        }
    if (l16 == 0) {
#pragma unroll
      for (int g = 0; g < 2; ++g)
#pragma unroll
        for (int r = 0; r < 4; ++r)
          sLa[(wc - 1) * 64 + wr * 32 + g * 16 + quad * 4 + r] = accL[g][r];
    }
  }
  __syncthreads();
  if (wc == 0) {
#pragma unroll
    for (int g = 0; g < 2; ++g) {
      float linv[4];
#pragma unroll
      for (int r = 0; r < 4; ++r) {
        const int rl = wr * 32 + g * 16 + quad * 4 + r;
        linv[r] = 1.0f / (accL[g][r] + sLa[rl] + sLa[64 + rl] + sLa[128 + rl]);
      }
#pragma unroll
      for (int t8 = 0; t8 < 8; ++t8)
#pragma unroll
        for (int r = 0; r < 4; ++r) {
          const int rl = wr * 32 + g * 16 + quad * 4 + r;
          const int c = t8 * 16 + l16;
          float o = accO[g][t8][r] + sO[rl * 128 + c] + sO[8192 + rl * 128 + c] +
                    sO[16384 + rl * 128 + c];
          combined_bf[(size_t)(row0 + rl) * HID + (8 + hj) * DH + c] =
              f2bf(o * linv[r]);
        }
    }
  }
}

// ---------------------------------------------------------------------------
// Fused vanilla attention (flash-style, fixed-shift softmax), restructured
// like lyra_attn: 2 row-waves x 4 key-waves, 128-key tiles (worst block
// 17 tiles vs 32).  Split-precision QK: kh from LDS, kl (residual) loaded
// per-lane from L2-resident Klo straight into registers (no LDS space/BW).
// Raw p (fp32) -> wout; exact row-sums via shfl; PV bf16.  Epilogue merges
// 4 wc-partials, writes normalized O and 1/rowsum (vnorm finishes wout).
// ---------------------------------------------------------------------------
__global__ __launch_bounds__(512) void vanilla_attn(
    const float* __restrict__ qkv,
    const short* __restrict__ Kbf,   // hi keys: rows 2048.. of Kbf
    const short* __restrict__ Klo,   // [4][2048][128] residuals, same swizzle
    const short* __restrict__ Vtb,   // cols 2048.. are current v
    float* __restrict__ wout,
    float* __restrict__ vinv,        // [8][2048] 1/rowsum
    short* __restrict__ combined_bf) {
  __shared__ short sKV[2][32768];    // 2 x (Khi 32KB | Vt 32KB)
  __shared__ short sP[8][2][1024];
  const int hj = blockIdx.x;
  const int qt = blockIdx.y;
  const int kvh = hj >> 1;
  const int t = threadIdx.x;
  const int w = t >> 6;
  const int lane = t & 63;
  const int quad = lane >> 4;
  const int l16 = lane & 15;
  const int wr = w >> 2;
  const int wc = w & 3;
  const int row0 = qt * 64;
  const int swx = (l16 & 7) << 4;
  const int voff = (wc >> 1) * 128 + ((((wc & 1) * 64) + quad * 16) ^ swx);
  const int nt = qt / 2 + 1;         // number of 128-key tiles (causal)

  // q hi/lo fragments, 2 row-groups
  bf16x8 qh[2][4], ql[2][4];
#pragma unroll
  for (int g = 0; g < 2; ++g) {
    const float* qrow =
        qkv + (size_t)(row0 + wr * 32 + g * 16 + l16) * QKV_W + hj * DH;
#pragma unroll
    for (int ks = 0; ks < 4; ++ks) {
#pragma unroll
      for (int e = 0; e < 8; ++e) {
        float x = qrow[ks * 32 + quad * 8 + e];
        short h = f2bf(x);
        qh[g][ks][e] = h;
        ql[g][ks][e] = f2bf(x - bf2f(h));
      }
    }
  }

  f32x4 accO[2][8];
#pragma unroll
  for (int g = 0; g < 2; ++g)
#pragma unroll
    for (int i = 0; i < 8; ++i) accO[g][i] = (f32x4){0.f, 0.f, 0.f, 0.f};
  float accR[2][4] = {{0.f, 0.f, 0.f, 0.f}, {0.f, 0.f, 0.f, 0.f}};

  const short* Kh = Kbf + ((size_t)kvh * 4096 + 2048) * DH;
  const short* Kl = Klo + (size_t)kvh * 2048 * DH;
  const short* Vb = Vtb + (size_t)kvh * DH * 4096 + 2048;  // current-v cols
  float* wrow = wout + (size_t)hj * S_LEN * S_LEN;

  stage_kv128(Kh, Vb, &sKV[0][0], 0, w, lane);

  int b = 0;
  for (int kt = 0; kt < nt; ++kt) {
    asm volatile("s_waitcnt vmcnt(0)" ::: "memory");
    __builtin_amdgcn_s_barrier();
    __builtin_amdgcn_sched_barrier(0);

    if (kt < nt - 1)
      stage_kv128(Kh, Vb, &sKV[b ^ 1][0], (kt + 1) * 128, w, lane);

    const int key0 = kt * 128;
    // kl residuals for this wave's 32 keys: per-lane L2 loads into regs
    bf16x8 klf[2][4];
#pragma unroll
    for (int s = 0; s < 2; ++s)
#pragma unroll
      for (int ks = 0; ks < 4; ++ks)
        klf[s][ks] = *(const bf16x8*)(
            Kl + (size_t)(key0 + wc * 32 + s * 16 + l16) * 128 +
            ((ks * 32 + quad * 8) ^ ((l16 & 7) << 3)));

    const char* Khs = (const char*)&sKV[b][0];
    const char* Vsc = (const char*)&sKV[b][16384];

    f32x4 accS[2][2];
#pragma unroll
    for (int g = 0; g < 2; ++g)
#pragma unroll
      for (int s = 0; s < 2; ++s) accS[g][s] = (f32x4){0.f, 0.f, 0.f, 0.f};
    __builtin_amdgcn_s_setprio(1);
#pragma unroll
    for (int s = 0; s < 2; ++s) {
      const char* krh = Khs + (wc * 32 + s * 16 + l16) * 256;
#pragma unroll
      for (int ks = 0; ks < 4; ++ks) {
        bf16x8 kh = *(const bf16x8*)(krh + ((ks * 64 + quad * 16) ^ swx));
        accS[0][s] = __builtin_amdgcn_mfma_f32_16x16x32_bf16(qh[0][ks], kh, accS[0][s], 0, 0, 0);
        accS[1][s] = __builtin_amdgcn_mfma_f32_16x16x32_bf16(qh[1][ks], kh, accS[1][s], 0, 0, 0);
        accS[0][s] = __builtin_amdgcn_mfma_f32_16x16x32_bf16(ql[0][ks], kh, accS[0][s], 0, 0, 0);
        accS[1][s] = __builtin_amdgcn_mfma_f32_16x16x32_bf16(ql[1][ks], kh, accS[1][s], 0, 0, 0);
        accS[0][s] = __builtin_amdgcn_mfma_f32_16x16x32_bf16(qh[0][ks], klf[s][ks], accS[0][s], 0, 0, 0);
        accS[1][s] = __builtin_amdgcn_mfma_f32_16x16x32_bf16(qh[1][ks], klf[s][ks], accS[1][s], 0, 0, 0);
      }
    }
    __builtin_amdgcn_s_setprio(0);

    // p = exp(s*SCALE - 12); causal zero on the diagonal tile; raw p -> wout
    const bool diag = (kt == nt - 1);
#pragma unroll
    for (int g = 0; g < 2; ++g) {
      short* sPg = &sP[w][g][0];
      float pr[4] = {0.f, 0.f, 0.f, 0.f};
#pragma unroll
      for (int s = 0; s < 2; ++s) {
        const int col = key0 + wc * 32 + s * 16 + l16;
#pragma unroll
        for (int r = 0; r < 4; ++r) {
          const int row = quad * 4 + r;
          const int grow = row0 + wr * 32 + g * 16 + row;
          float p = __expf(accS[g][s][r] * SCALE - LYRA_C);
          if (diag && col > grow) p = 0.f;
          pr[r] += p;
          const int sl = (s * 2 + (l16 >> 3)) ^ (row & 7);
          sPg[row * 64 + sl * 8 + (l16 & 7)] = f2bf(p);
          wrow[(size_t)grow * S_LEN + col] = p;
        }
      }
#pragma unroll
      for (int r = 0; r < 4; ++r) {
        float v = pr[r];
        v += __shfl_xor(v, 1);
        v += __shfl_xor(v, 2);
        v += __shfl_xor(v, 4);
        v += __shfl_xor(v, 8);
        accR[g][r] += v;
      }
    }

    // PV over this wave's 32-key slice
    __builtin_amdgcn_s_setprio(1);
    bf16x8 ap0 = *(const bf16x8*)&sP[w][0][l16 * 64 + ((quad ^ (l16 & 7)) << 3)];
    bf16x8 ap1 = *(const bf16x8*)&sP[w][1][l16 * 64 + ((quad ^ (l16 & 7)) << 3)];
#pragma unroll
    for (int t8 = 0; t8 < 8; ++t8) {
      bf16x8 bv = *(const bf16x8*)(Vsc + (t8 * 16 + l16) * 256 + voff);
      accO[0][t8] = __builtin_amdgcn_mfma_f32_16x16x32_bf16(ap0, bv, accO[0][t8], 0, 0, 0);
      accO[1][t8] = __builtin_amdgcn_mfma_f32_16x16x32_bf16(ap1, bv, accO[1][t8], 0, 0, 0);
    }
    __builtin_amdgcn_s_setprio(0);

    b ^= 1;
  }

  // epilogue: merge 4 wc-partials; write normalized O and 1/rowsum.
  __syncthreads();
  float* sO = (float*)&sKV[0][0];
  float* sLa = (float*)&sP[0][0][0];  // [3][64]
  if (wc != 0) {
    float* dst = sO + (size_t)(wc - 1) * 8192;
#pragma unroll
    for (int g = 0; g < 2; ++g)
#pragma unroll
      for (int t8 = 0; t8 < 8; ++t8)
#pragma unroll
        for (int r = 0; r < 4; ++r) {
          const int rl = wr * 32 + g * 16 + quad * 4 + r;
          dst[rl * 128 + t8 * 16 + l16] = accO[g][t8][r];
        }
    if (l16 == 0) {
#pragma unroll
      for (int g = 0; g < 2; ++g)
#pragma unroll
        for (int r = 0; r < 4; ++r)
          sLa[(wc - 1) * 64 + wr * 32 + g * 16 + quad * 4 + r] = accR[g][r];
    }
  }
  __syncthreads();
  if (wc == 0) {
#pragma unroll
    for (int g = 0; g < 2; ++g) {
      float linv[4];
#pragma unroll
      for (int r = 0; r < 4; ++r) {
        const int rl = wr * 32 + g * 16 + quad * 4 + r;
        linv[r] = 1.0f / (accR[g][r] + sLa[rl] + sLa[64 + rl] + sLa[128 + rl]);
      }
      if (l16 == 0) {
#pragma unroll
        for (int r = 0; r < 4; ++r)
          vinv[hj * S_LEN + row0 + wr * 32 + g * 16 + quad * 4 + r] = linv[r];
      }
#pragma unroll
      for (int t8 = 0; t8 < 8; ++t8)
#pragma unroll
        for (int r = 0; r < 4; ++r) {
          const int rl = wr * 32 + g * 16 + quad * 4 + r;
          const int c = t8 * 16 + l16;
          float o = accO[g][t8][r] + sO[rl * 128 + c] + sO[8192 + rl * 128 + c] +
                    sO[16384 + rl * 128 + c];
          combined_bf[(size_t)(row0 + rl) * HID + hj * DH + c] =
              f2bf(o * linv[r]);
        }
    }
  }
}

// ---------------------------------------------------------------------------
// Normalize vanilla_w rows by stored 1/rowsum; zero-fill j > row.
// ---------------------------------------------------------------------------
__global__ __launch_bounds__(256) void vnorm(
    const float* __restrict__ vinv, float* __restrict__ wout) {
  const int row = blockIdx.x;
  const int h = blockIdx.y;
  float* p = wout + (size_t)h * S_LEN * S_LEN + (size_t)row * S_LEN;
  const float inv = vinv[h * S_LEN + row];
  const int t = threadIdx.x;
#pragma unroll
  for (int i = 0; i < 2; ++i) {
    const int j = (t + i * 256) * 4;
    float4 v;
    if (j > row) {
      v = make_float4(0.f, 0.f, 0.f, 0.f);
    } else if (j + 3 <= row) {
      v = *(const float4*)(p + j);
      v.x *= inv; v.y *= inv; v.z *= inv; v.w *= inv;
    } else {
      v = *(const float4*)(p + j);
      v.x = (j + 0 <= row) ? v.x * inv : 0.f;
      v.y = (j + 1 <= row) ? v.y * inv : 0.f;
      v.z = (j + 2 <= row) ? v.z * inv : 0.f;
      v.w = (j + 3 <= row) ? v.w * inv : 0.f;
    }
    *(float4*)(p + j) = v;
  }
}

// ---------------------------------------------------------------------------
extern "C" void kernel_launch(void* const* d_in, const int* in_sizes, int n_in,
                              void* d_out, int out_size, void* d_ws, size_t ws_size,
                              hipStream_t stream) {
  (void)in_sizes; (void)n_in; (void)out_size; (void)ws_size;
  const float* hidden = (const float*)d_in[0];
  const float* cosb   = (const float*)d_in[1];
  const float* sinb   = (const float*)d_in[2];
  const float* kcache = (const float*)d_in[4];
  const float* vcache = (const float*)d_in[5];
  const float* Wq = (const float*)d_in[6];
  const float* Wk = (const float*)d_in[7];
  const float* Wv = (const float*)d_in[8];
  const float* Wo = (const float*)d_in[9];
  const float* qw = (const float*)d_in[10];
  const float* kw = (const float*)d_in[11];

  float* out  = (float*)d_out;                     // attn_output [2048*2048]
  float* wout = out + (size_t)4194304;             // vanilla_w   [8*2048*2048]

  // d_ws: qkv f32 | Kbf | Vtb | combined_bf | Wo_bf
  float* qkv = (float*)d_ws;                       // [2048 x 3072] f32
  short* Kbf = (short*)(qkv + (size_t)2048 * QKV_W);
  short* Vtb = Kbf + (size_t)4 * 4096 * DH;
  short* combined_bf = Vtb + (size_t)4 * DH * 4096;   // [2048 x 2048] bf16
  short* Wo_bf = combined_bf + (size_t)2048 * HID;    // [2048 x 2048] bf16

  // transient scratch inside wout (consumed by gemm qkv before vanilla_attn
  // overwrites wout):
  short* hidden_bf = (short*)wout;                    // [2048 x 2048] bf16
  short* Wqkv_bf = hidden_bf + (size_t)2048 * HID;    // [3072 x 2048] bf16

  // transient scratch inside attn_output (dead before final gemm writes it):
  short* Klo  = (short*)out;                          // [4][2048][128] bf16 = 2 MB
  float* vinv = (float*)(Klo + (size_t)4 * 2048 * DH); // [8][2048] f32 = 64 KB

  pack_bf16<<<dim3(2048), 256, 0, stream>>>(hidden, hidden_bf);
  pack_bf16<<<dim3(2048), 256, 0, stream>>>(Wq, Wqkv_bf);
  pack_bf16<<<dim3(512), 256, 0, stream>>>(Wk, Wqkv_bf + (size_t)2048 * 2048);
  pack_bf16<<<dim3(512), 256, 0, stream>>>(Wv, Wqkv_bf + (size_t)2560 * 2048);
  pack_bf16<<<dim3(2048), 256, 0, stream>>>(Wo, Wo_bf);

  gemm_bf16<<<dim3(24, 16), 256, 0, stream>>>(hidden_bf, Wqkv_bf, qkv, 2048, QKV_W);
  rms_rope<<<dim3(10240), 256, 0, stream>>>(qkv, cosb, sinb, qw, kw);
  pack_k<<<dim3(2048), 256, 0, stream>>>(qkv, kcache, Kbf, Klo);
  pack_vt<<<dim3(64, 2, 4), 256, 0, stream>>>(qkv, vcache, Vtb);
  lyra_attn<<<dim3(8, 32), 512, 0, stream>>>(qkv, Kbf, Vtb, combined_bf);
  vanilla_attn<<<dim3(8, 32), 512, 0, stream>>>(qkv, Kbf, Klo, Vtb, wout, vinv,
                                                combined_bf);
  vnorm<<<dim3(2048, 8), 256, 0, stream>>>(vinv, wout);
  gemm_bf16<<<dim3(16, 16), 256, 0, stream>>>(combined_bf, Wo_bf, out, 2048, HID);
}